// Round 1
// baseline (2885.173 us; speedup 1.0000x reference)
//
#include <hip/hip_runtime.h>
#include <hip/hip_bf16.h>

typedef unsigned short u16;
typedef unsigned int u32;
typedef __bf16 bf16x8 __attribute__((ext_vector_type(8)));
typedef float f32x4 __attribute__((ext_vector_type(4)));
typedef u32 u32x4 __attribute__((ext_vector_type(4)));
typedef u32 u32x2 __attribute__((ext_vector_type(2)));

__device__ __forceinline__ u16 f2bf(float f) {
  __hip_bfloat16 h = __float2bfloat16(f);
  return *reinterpret_cast<u16*>(&h);
}
__device__ __forceinline__ float bf2f(u16 u) {
  return __uint_as_float(((u32)u) << 16);
}

// ---------------------------------------------------------------------------
// Transpose + cast fp32 (R x C) -> bf16 (C x R)
// ---------------------------------------------------------------------------
__global__ __launch_bounds__(256) void transpose_cast(
    const float* __restrict__ in, u16* __restrict__ out, int R, int C) {
  __shared__ float tile[32][33];
  int c0 = blockIdx.x * 32, r0 = blockIdx.y * 32;
  int tx = threadIdx.x & 31, ty = threadIdx.x >> 5;  // ty 0..7
  for (int i = ty; i < 32; i += 8) {
    int r = r0 + i, c = c0 + tx;
    if (r < R && c < C) tile[i][tx] = in[(size_t)r * C + c];
  }
  __syncthreads();
  for (int i = ty; i < 32; i += 8) {
    int c = c0 + i, r = r0 + tx;
    if (c < C && r < R) out[(size_t)c * R + r] = f2bf(tile[tx][i]);
  }
}

// ---------------------------------------------------------------------------
// LayerNorm over last dim (1024), fp32 in -> bf16 out. One block per row.
// ---------------------------------------------------------------------------
__global__ __launch_bounds__(256) void ln_kernel(
    const float* __restrict__ x, const float* __restrict__ g,
    const float* __restrict__ bb, u16* __restrict__ out) {
  __shared__ float red[8];
  const int row = blockIdx.x;
  const float* xr = x + (size_t)row * 1024;
  f32x4 v = *(const f32x4*)(xr + threadIdx.x * 4);
  float s = v[0] + v[1] + v[2] + v[3];
  for (int off = 32; off > 0; off >>= 1) s += __shfl_xor(s, off, 64);
  if ((threadIdx.x & 63) == 0) red[threadIdx.x >> 6] = s;
  __syncthreads();
  float mu = (red[0] + red[1] + red[2] + red[3]) * (1.0f / 1024.0f);
  f32x4 d;
  d[0] = v[0] - mu; d[1] = v[1] - mu; d[2] = v[2] - mu; d[3] = v[3] - mu;
  float sq = d[0]*d[0] + d[1]*d[1] + d[2]*d[2] + d[3]*d[3];
  for (int off = 32; off > 0; off >>= 1) sq += __shfl_xor(sq, off, 64);
  if ((threadIdx.x & 63) == 0) red[4 + (threadIdx.x >> 6)] = sq;
  __syncthreads();
  float var = (red[4] + red[5] + red[6] + red[7]) * (1.0f / 1024.0f);
  float rstd = rsqrtf(var + 1e-5f);
  int cb = threadIdx.x * 4;
  for (int e = 0; e < 4; ++e)
    out[(size_t)row * 1024 + cb + e] = f2bf(d[e] * rstd * g[cb + e] + bb[cb + e]);
}

// ---------------------------------------------------------------------------
// bf16 MFMA GEMM: C[M,N] = A[M,K] * Bt[N,K]^T + bias, fused epilogues.
// 128x128 tile, BK=32, 256 threads = 4 waves in 2x2, each wave 4x4 of 16x16x32.
// mode 0: fp32 out = acc+bias      mode 1: fp32 out = acc+bias+res
// mode 2: bf16 out = gelu(acc+bias)
// ---------------------------------------------------------------------------
#define LDT 40  // padded LDS row (shorts): 2-way bank conflicts only (free)

__global__ __launch_bounds__(256) void gemm_bt(
    const u16* __restrict__ A, const u16* __restrict__ Bt,
    const float* __restrict__ bias, const float* __restrict__ res,
    void* __restrict__ outp, int M, int N, int K, int mode) {
  __shared__ u16 As[128 * LDT];
  __shared__ u16 Bs[128 * LDT];
  const int tid = threadIdx.x;
  const int m0 = blockIdx.y * 128, n0 = blockIdx.x * 128;
  const int wave = tid >> 6, lane = tid & 63;
  const int wm = (wave >> 1) * 64, wn = (wave & 1) * 64;
  const int lr = lane & 15, quad = lane >> 4;
  const int sr = tid >> 2;           // staging row 0..63
  const int scc = (tid & 3) * 8;     // staging col {0,8,16,24}

  f32x4 acc[4][4] = {};

  for (int k0 = 0; k0 < K; k0 += 32) {
    for (int pass = 0; pass < 2; ++pass) {
      int r = sr + pass * 64;
      u32x4 av = *(const u32x4*)(A + (size_t)(m0 + r) * K + k0 + scc);
      u32x4 bv = *(const u32x4*)(Bt + (size_t)(n0 + r) * K + k0 + scc);
      u32* ap = (u32*)&As[r * LDT + scc];
      u32* bp = (u32*)&Bs[r * LDT + scc];
      *(u32x2*)ap = (u32x2){av[0], av[1]};
      *(u32x2*)(ap + 2) = (u32x2){av[2], av[3]};
      *(u32x2*)bp = (u32x2){bv[0], bv[1]};
      *(u32x2*)(bp + 2) = (u32x2){bv[2], bv[3]};
    }
    __syncthreads();
    bf16x8 af[4], bfr[4];
    for (int t = 0; t < 4; ++t) {
      af[t]  = *(const bf16x8*)&As[(wm + t * 16 + lr) * LDT + quad * 8];
      bfr[t] = *(const bf16x8*)&Bs[(wn + t * 16 + lr) * LDT + quad * 8];
    }
    for (int mt = 0; mt < 4; ++mt)
      for (int nt = 0; nt < 4; ++nt)
        acc[mt][nt] = __builtin_amdgcn_mfma_f32_16x16x32_bf16(
            af[mt], bfr[nt], acc[mt][nt], 0, 0, 0);
    __syncthreads();
  }

  for (int mt = 0; mt < 4; ++mt) {
    for (int nt = 0; nt < 4; ++nt) {
      const int col = n0 + wn + nt * 16 + lr;
      const float bvv = bias[col];
      for (int rr = 0; rr < 4; ++rr) {
        const int row = m0 + wm + mt * 16 + quad * 4 + rr;
        const size_t idx = (size_t)row * N + col;
        float v = acc[mt][nt][rr] + bvv;
        if (mode == 0) {
          ((float*)outp)[idx] = v;
        } else if (mode == 1) {
          ((float*)outp)[idx] = v + res[idx];
        } else {  // GELU (exact) -> bf16
          float gl = 0.5f * v * (1.0f + erff(v * 0.70710678118654752f));
          ((u16*)outp)[idx] = f2bf(gl);
        }
      }
    }
  }
}

// ---------------------------------------------------------------------------
// logf = log_sigmoid(h @ wf + bf), one wave per row. wfT is (16 x 1024) bf16.
// Writes into c buffer (B*S, 16) fp32.
// ---------------------------------------------------------------------------
__global__ __launch_bounds__(64) void logf_kernel(
    const u16* __restrict__ h, const u16* __restrict__ wfT,
    const float* __restrict__ bfv, float* __restrict__ c) {
  const int row = blockIdx.x;
  const int lane = threadIdx.x;
  float acc[16];
  for (int n = 0; n < 16; ++n) acc[n] = 0.f;
  for (int t = 0; t < 16; ++t) {
    int kidx = t * 64 + lane;
    float hv = bf2f(h[(size_t)row * 1024 + kidx]);
    for (int n = 0; n < 16; ++n)
      acc[n] += hv * bf2f(wfT[n * 1024 + kidx]);
  }
  float z = 0.f;
  for (int n = 0; n < 16; ++n) {
    float r = acc[n];
    for (int off = 1; off < 64; off <<= 1) r += __shfl_xor(r, off, 64);
    if (lane == n) z = r;
  }
  if (lane < 16) {
    z += bfv[lane];
    float lf = (z >= 0.f) ? -log1pf(expf(-z)) : (z - log1pf(expf(z)));
    c[(size_t)row * 16 + lane] = lf;
  }
}

// ---------------------------------------------------------------------------
// In-place inclusive cumsum of c over the sequence dim, per (b, h).
// ---------------------------------------------------------------------------
__global__ __launch_bounds__(64) void cumsum_kernel(float* __restrict__ c, int S) {
  const int b = blockIdx.x >> 4, h = blockIdx.x & 15;
  const int lane = threadIdx.x;
  float carry = 0.f;
  for (int s0 = 0; s0 < S; s0 += 64) {
    float v = c[(size_t)(b * S + s0 + lane) * 16 + h];
    for (int off = 1; off < 64; off <<= 1) {
      float t = __shfl_up(v, off, 64);
      if (lane >= off) v += t;
    }
    v += carry;
    c[(size_t)(b * S + s0 + lane) * 16 + h] = v;
    carry = __shfl(v, 63, 64);
  }
}

// ---------------------------------------------------------------------------
// Flash attention with forget-gate decay bias. fp32 vector math.
// Grid: (S/64, B*H). 64-query x 32-key tiles. Output ctx as bf16 (B,S,H,Dh).
// ---------------------------------------------------------------------------
#define QS 76        // fp32 LDS row stride (pad: all b128 reads <=2-way)
#define PSS 36       // P tile stride

__global__ __launch_bounds__(256) void fattn(
    const float* __restrict__ q, const float* __restrict__ k,
    const float* __restrict__ v, const float* __restrict__ c,
    u16* __restrict__ ctx) {
  __shared__ float Qs[64 * QS];
  __shared__ float Ks[32 * QS];
  __shared__ float Vs[32 * QS];
  __shared__ float Psh[64 * PSS];
  __shared__ float cjs[32];
  const int S = 2048;
  const int b = blockIdx.y >> 4, h = blockIdx.y & 15;
  const int i0 = blockIdx.x * 64;
  const int tid = threadIdx.x;
  const int ty = tid >> 4, tx = tid & 15;

  for (int t = tid; t < 1024; t += 256) {
    int r = t >> 4, c4 = (t & 15) * 4;
    *(f32x4*)&Qs[r * QS + c4] =
        *(const f32x4*)&q[((size_t)(b * S + i0 + r) * 1024) + h * 64 + c4];
  }
  float ci[4], m_[4], l_[4], o_[4][4];
  for (int a = 0; a < 4; ++a) {
    ci[a] = c[(size_t)(b * S + i0 + 4 * ty + a) * 16 + h];
    m_[a] = -INFINITY; l_[a] = 0.f;
    for (int d = 0; d < 4; ++d) o_[a][d] = 0.f;
  }
  const int ntiles = 2 * (blockIdx.x + 1);
  for (int jt = 0; jt < ntiles; ++jt) {
    const int j0 = jt * 32;
    for (int t = tid; t < 512; t += 256) {
      int r = t >> 4, c4 = (t & 15) * 4;
      size_t g = ((size_t)(b * S + j0 + r) * 1024) + h * 64 + c4;
      *(f32x4*)&Ks[r * QS + c4] = *(const f32x4*)&k[g];
      *(f32x4*)&Vs[r * QS + c4] = *(const f32x4*)&v[g];
    }
    if (tid < 32) cjs[tid] = c[(size_t)(b * S + j0 + tid) * 16 + h];
    __syncthreads();

    float sc[4][2] = {};
    for (int kk = 0; kk < 64; kk += 4) {
      f32x4 qv[4], kv[2];
      for (int a = 0; a < 4; ++a) qv[a] = *(const f32x4*)&Qs[(4 * ty + a) * QS + kk];
      kv[0] = *(const f32x4*)&Ks[tx * QS + kk];
      kv[1] = *(const f32x4*)&Ks[(tx + 16) * QS + kk];
      for (int a = 0; a < 4; ++a)
        for (int b2 = 0; b2 < 2; ++b2)
          sc[a][b2] += qv[a][0] * kv[b2][0] + qv[a][1] * kv[b2][1] +
                       qv[a][2] * kv[b2][2] + qv[a][3] * kv[b2][3];
    }
    const bool maskt = (j0 >= i0);
    float alpha[4];
    for (int a = 0; a < 4; ++a) {
      const int i = i0 + 4 * ty + a;
      float lg[2];
      for (int b2 = 0; b2 < 2; ++b2) {
        const int j = j0 + tx + 16 * b2;
        float vv = sc[a][b2] * 0.125f + ci[a] - cjs[tx + 16 * b2];
        if (maskt && (j > i)) vv = -INFINITY;
        lg[b2] = vv;
      }
      float mx = fmaxf(lg[0], lg[1]);
      for (int off = 1; off < 16; off <<= 1) mx = fmaxf(mx, __shfl_xor(mx, off, 64));
      const float mn = fmaxf(m_[a], mx);
      alpha[a] = __expf(m_[a] - mn);
      float rs = 0.f;
      for (int b2 = 0; b2 < 2; ++b2) {
        float p = __expf(lg[b2] - mn);
        Psh[(4 * ty + a) * PSS + tx + 16 * b2] = p;
        rs += p;
      }
      for (int off = 1; off < 16; off <<= 1) rs += __shfl_xor(rs, off, 64);
      l_[a] = l_[a] * alpha[a] + rs;
      m_[a] = mn;
    }
    __syncthreads();
    for (int a = 0; a < 4; ++a)
      for (int d = 0; d < 4; ++d) o_[a][d] *= alpha[a];
    for (int jj = 0; jj < 32; jj += 4) {
      f32x4 vr[4];
      for (int e = 0; e < 4; ++e) vr[e] = *(const f32x4*)&Vs[(jj + e) * QS + 4 * tx];
      for (int a = 0; a < 4; ++a) {
        f32x4 p4 = *(const f32x4*)&Psh[(4 * ty + a) * PSS + jj];
        for (int d = 0; d < 4; ++d)
          o_[a][d] += p4[0] * vr[0][d] + p4[1] * vr[1][d] +
                      p4[2] * vr[2][d] + p4[3] * vr[3][d];
      }
    }
    __syncthreads();
  }
  for (int a = 0; a < 4; ++a) {
    float inv = 1.0f / l_[a];
    size_t base = ((size_t)(b * S + i0 + 4 * ty + a) * 1024) + h * 64 + 4 * tx;
    for (int d = 0; d < 4; ++d) ctx[base + d] = f2bf(o_[a][d] * inv);
  }
}

// ---------------------------------------------------------------------------
extern "C" void kernel_launch(void* const* d_in, const int* in_sizes, int n_in,
                              void* d_out, int out_size, void* d_ws, size_t ws_size,
                              hipStream_t stream) {
  const float* x    = (const float*)d_in[0];
  const float* ln1g = (const float*)d_in[1];
  const float* ln1b = (const float*)d_in[2];
  const float* wq   = (const float*)d_in[3];
  const float* bq   = (const float*)d_in[4];
  const float* wk   = (const float*)d_in[5];
  const float* bk   = (const float*)d_in[6];
  const float* wv   = (const float*)d_in[7];
  const float* bv   = (const float*)d_in[8];
  const float* wo   = (const float*)d_in[9];
  const float* bo   = (const float*)d_in[10];
  const float* wf   = (const float*)d_in[11];
  const float* bfv  = (const float*)d_in[12];
  const float* ln2g = (const float*)d_in[13];
  const float* ln2b = (const float*)d_in[14];
  const float* w1   = (const float*)d_in[15];
  const float* b1   = (const float*)d_in[16];
  const float* w2   = (const float*)d_in[17];
  const float* b2   = (const float*)d_in[18];
  float* out = (float*)d_out;

  char* ws = (char*)d_ws;
  const size_t MB = 1024 * 1024;
  u16*   wqT  = (u16*)(ws + 0 * MB);    // 1024x1024 bf16
  u16*   wkT  = (u16*)(ws + 2 * MB);
  u16*   wvT  = (u16*)(ws + 4 * MB);
  u16*   woT  = (u16*)(ws + 6 * MB);
  u16*   w1T  = (u16*)(ws + 8 * MB);    // 4096x1024 bf16
  u16*   w2T  = (u16*)(ws + 16 * MB);   // 1024x4096 bf16
  u16*   wfT  = (u16*)(ws + 24 * MB);   // 16x1024 bf16
  u16*   hbuf = (u16*)(ws + 25 * MB);   // 4096x1024 bf16 (h1, then h2)
  u16*   ctx  = (u16*)(ws + 33 * MB);   // 4096x1024 bf16
  float* qb   = (float*)(ws + 41 * MB); // 4096x1024 fp32
  float* kb   = (float*)(ws + 57 * MB);
  float* vb   = (float*)(ws + 73 * MB);
  float* cb   = (float*)(ws + 89 * MB); // 4096x16 fp32
  u16*   act1 = (u16*)(ws + 90 * MB);   // 4096x4096 bf16

  dim3 blk(256);
  // weight prep (transpose + bf16 cast)
  transpose_cast<<<dim3(32, 32), blk, 0, stream>>>(wq, wqT, 1024, 1024);
  transpose_cast<<<dim3(32, 32), blk, 0, stream>>>(wk, wkT, 1024, 1024);
  transpose_cast<<<dim3(32, 32), blk, 0, stream>>>(wv, wvT, 1024, 1024);
  transpose_cast<<<dim3(32, 32), blk, 0, stream>>>(wo, woT, 1024, 1024);
  transpose_cast<<<dim3(128, 32), blk, 0, stream>>>(w1, w1T, 1024, 4096);
  transpose_cast<<<dim3(32, 128), blk, 0, stream>>>(w2, w2T, 4096, 1024);
  transpose_cast<<<dim3(1, 32), blk, 0, stream>>>(wf, wfT, 1024, 16);
  // LN1
  ln_kernel<<<4096, blk, 0, stream>>>(x, ln1g, ln1b, hbuf);
  // QKV projections (fp32 out)
  gemm_bt<<<dim3(8, 32), blk, 0, stream>>>(hbuf, wqT, bq, nullptr, qb, 4096, 1024, 1024, 0);
  gemm_bt<<<dim3(8, 32), blk, 0, stream>>>(hbuf, wkT, bk, nullptr, kb, 4096, 1024, 1024, 0);
  gemm_bt<<<dim3(8, 32), blk, 0, stream>>>(hbuf, wvT, bv, nullptr, vb, 4096, 1024, 1024, 0);
  // forget gate: logf then cumsum
  logf_kernel<<<4096, dim3(64), 0, stream>>>(hbuf, wfT, bfv, cb);
  cumsum_kernel<<<32, dim3(64), 0, stream>>>(cb, 2048);
  // attention
  fattn<<<dim3(32, 32), blk, 0, stream>>>(qb, kb, vb, cb, ctx);
  // out projection + residual -> d_out (= x1)
  gemm_bt<<<dim3(8, 32), blk, 0, stream>>>(ctx, woT, bo, x, out, 4096, 1024, 1024, 1);
  // LN2
  ln_kernel<<<4096, blk, 0, stream>>>(out, ln2g, ln2b, hbuf);
  // MLP: h2@w1 + b1 -> GELU -> bf16
  gemm_bt<<<dim3(32, 32), blk, 0, stream>>>(hbuf, w1T, b1, nullptr, act1, 4096, 4096, 1024, 2);
  // act1@w2 + b2 + x1 -> d_out
  gemm_bt<<<dim3(8, 32), blk, 0, stream>>>(act1, w2T, b2, out, out, 4096, 1024, 4096, 1);
}

// Round 2
// 2232.850 us; speedup vs baseline: 1.2921x; 1.2921x over previous
//
#include <hip/hip_runtime.h>
#include <hip/hip_bf16.h>
#include <math.h>

typedef unsigned short u16;
typedef unsigned int u32;
typedef __bf16 bf16x8 __attribute__((ext_vector_type(8)));
typedef float f32x4 __attribute__((ext_vector_type(4)));
typedef u32 u32x4 __attribute__((ext_vector_type(4)));

__device__ __forceinline__ u16 f2bf(float f) {
  __hip_bfloat16 h = __float2bfloat16(f);
  return *reinterpret_cast<u16*>(&h);
}
__device__ __forceinline__ float bf2f(u16 u) {
  return __uint_as_float(((u32)u) << 16);
}

// async global->LDS, 16B per lane; LDS dest = wave-uniform base + lane*16
#define GLL(gp, lp)                                                     \
  __builtin_amdgcn_global_load_lds(                                     \
      (const __attribute__((address_space(1))) void*)(gp),              \
      (__attribute__((address_space(3))) void*)(lp), 16, 0, 0)

// ---------------------------------------------------------------------------
// Transpose + cast fp32 (R x C) -> bf16 (C x R)
// ---------------------------------------------------------------------------
__global__ __launch_bounds__(256) void transpose_cast(
    const float* __restrict__ in, u16* __restrict__ out, int R, int C) {
  __shared__ float tile[32][33];
  int c0 = blockIdx.x * 32, r0 = blockIdx.y * 32;
  int tx = threadIdx.x & 31, ty = threadIdx.x >> 5;
  for (int i = ty; i < 32; i += 8) {
    int r = r0 + i, c = c0 + tx;
    if (r < R && c < C) tile[i][tx] = in[(size_t)r * C + c];
  }
  __syncthreads();
  for (int i = ty; i < 32; i += 8) {
    int c = c0 + i, r = r0 + tx;
    if (c < C && r < R) out[(size_t)c * R + r] = f2bf(tile[tx][i]);
  }
}

// pack bq,bk,bv -> 3072-float bias
__global__ __launch_bounds__(256) void pack3(
    const float* __restrict__ a, const float* __restrict__ b,
    const float* __restrict__ c, float* __restrict__ o) {
  int t = blockIdx.x * 256 + threadIdx.x;
  if (t < 1024) o[t] = a[t];
  else if (t < 2048) o[t] = b[t - 1024];
  else if (t < 3072) o[t] = c[t - 2048];
}

// ---------------------------------------------------------------------------
// LayerNorm over last dim (1024), fp32 in -> bf16 out. One block per row.
// ---------------------------------------------------------------------------
__global__ __launch_bounds__(256) void ln_kernel(
    const float* __restrict__ x, const float* __restrict__ g,
    const float* __restrict__ bb, u16* __restrict__ out) {
  __shared__ float red[8];
  const int row = blockIdx.x;
  const float* xr = x + (size_t)row * 1024;
  f32x4 v = *(const f32x4*)(xr + threadIdx.x * 4);
  float s = v[0] + v[1] + v[2] + v[3];
  for (int off = 32; off > 0; off >>= 1) s += __shfl_xor(s, off, 64);
  if ((threadIdx.x & 63) == 0) red[threadIdx.x >> 6] = s;
  __syncthreads();
  float mu = (red[0] + red[1] + red[2] + red[3]) * (1.0f / 1024.0f);
  f32x4 d;
  d[0] = v[0] - mu; d[1] = v[1] - mu; d[2] = v[2] - mu; d[3] = v[3] - mu;
  float sq = d[0]*d[0] + d[1]*d[1] + d[2]*d[2] + d[3]*d[3];
  for (int off = 32; off > 0; off >>= 1) sq += __shfl_xor(sq, off, 64);
  if ((threadIdx.x & 63) == 0) red[4 + (threadIdx.x >> 6)] = sq;
  __syncthreads();
  float var = (red[4] + red[5] + red[6] + red[7]) * (1.0f / 1024.0f);
  float rstd = rsqrtf(var + 1e-5f);
  int cb = threadIdx.x * 4;
  for (int e = 0; e < 4; ++e)
    out[(size_t)row * 1024 + cb + e] = f2bf(d[e] * rstd * g[cb + e] + bb[cb + e]);
}

// ---------------------------------------------------------------------------
// bf16 MFMA GEMM with global_load_lds width-16 staging (m97 structure).
// C[M,N] = A[M,K] * Bt[N,K]^T + bias. 128x128 tile, BK=32, 4 waves 2x2,
// each wave 4x4 of 16x16x32.
// mode 0: fp32 out          mode 1: fp32 out + res
// mode 2: bf16 out = gelu   mode 3: bf16 out
// ---------------------------------------------------------------------------
__global__ __launch_bounds__(256) void gemm_bt(
    const u16* __restrict__ A, const u16* __restrict__ Bt,
    const float* __restrict__ bias, const float* __restrict__ res,
    void* __restrict__ outp, int M, int N, int K, int mode) {
  __shared__ u16 As[128 * 32];
  __shared__ u16 Bs[128 * 32];
  const int tid = threadIdx.x;
  const int m0 = blockIdx.y * 128, n0 = blockIdx.x * 128;
  const int wave = tid >> 6, lane = tid & 63;
  const int wm = (wave >> 1) * 64, wn = (wave & 1) * 64;
  const int lr = lane & 15, quad = lane >> 4;
  // staging: 8 groups of 16 rows (1024B each); wave w stages groups 2w, 2w+1
  const int g0 = wave * 2;
  const int srow0 = g0 * 16 + (lane >> 2);
  const int scol = (lane & 3) * 8;
  const u16* Ag0 = A + (size_t)(m0 + srow0) * K + scol;
  const u16* Ag1 = A + (size_t)(m0 + srow0 + 16) * K + scol;
  const u16* Bg0 = Bt + (size_t)(n0 + srow0) * K + scol;
  const u16* Bg1 = Bt + (size_t)(n0 + srow0 + 16) * K + scol;
  u16* Al0 = As + g0 * 512;
  u16* Al1 = As + (g0 + 1) * 512;
  u16* Bl0 = Bs + g0 * 512;
  u16* Bl1 = Bs + (g0 + 1) * 512;

  f32x4 acc[4][4] = {};

  for (int k0 = 0; k0 < K; k0 += 32) {
    GLL(Ag0 + k0, Al0);
    GLL(Ag1 + k0, Al1);
    GLL(Bg0 + k0, Bl0);
    GLL(Bg1 + k0, Bl1);
    __syncthreads();
    bf16x8 af[4], bfr[4];
    for (int t = 0; t < 4; ++t) {
      af[t]  = *(const bf16x8*)&As[(wm + t * 16 + lr) * 32 + quad * 8];
      bfr[t] = *(const bf16x8*)&Bs[(wn + t * 16 + lr) * 32 + quad * 8];
    }
    for (int mt = 0; mt < 4; ++mt)
      for (int nt = 0; nt < 4; ++nt)
        acc[mt][nt] = __builtin_amdgcn_mfma_f32_16x16x32_bf16(
            af[mt], bfr[nt], acc[mt][nt], 0, 0, 0);
    __syncthreads();
  }

  for (int mt = 0; mt < 4; ++mt) {
    for (int nt = 0; nt < 4; ++nt) {
      const int col = n0 + wn + nt * 16 + lr;
      const float bvv = bias[col];
      for (int rr = 0; rr < 4; ++rr) {
        const int row = m0 + wm + mt * 16 + quad * 4 + rr;
        const size_t idx = (size_t)row * N + col;
        float v = acc[mt][nt][rr] + bvv;
        if (mode == 0) {
          ((float*)outp)[idx] = v;
        } else if (mode == 1) {
          ((float*)outp)[idx] = v + res[idx];
        } else if (mode == 2) {
          float gl = 0.5f * v * (1.0f + erff(v * 0.70710678118654752f));
          ((u16*)outp)[idx] = f2bf(gl);
        } else {
          ((u16*)outp)[idx] = f2bf(v);
        }
      }
    }
  }
}

// ---------------------------------------------------------------------------
// logf = log_sigmoid(h @ wf + bf), one wave per row. wfT is (16 x 1024) bf16.
// ---------------------------------------------------------------------------
__global__ __launch_bounds__(64) void logf_kernel(
    const u16* __restrict__ h, const u16* __restrict__ wfT,
    const float* __restrict__ bfv, float* __restrict__ c) {
  const int row = blockIdx.x;
  const int lane = threadIdx.x;
  float acc[16];
  for (int n = 0; n < 16; ++n) acc[n] = 0.f;
  for (int t = 0; t < 16; ++t) {
    int kidx = t * 64 + lane;
    float hv = bf2f(h[(size_t)row * 1024 + kidx]);
    for (int n = 0; n < 16; ++n)
      acc[n] += hv * bf2f(wfT[n * 1024 + kidx]);
  }
  float z = 0.f;
  for (int n = 0; n < 16; ++n) {
    float r = acc[n];
    for (int off = 1; off < 64; off <<= 1) r += __shfl_xor(r, off, 64);
    if (lane == n) z = r;
  }
  if (lane < 16) {
    z += bfv[lane];
    float lf = (z >= 0.f) ? -log1pf(expf(-z)) : (z - log1pf(expf(z)));
    c[(size_t)row * 16 + lane] = lf;
  }
}

__global__ __launch_bounds__(64) void cumsum_kernel(float* __restrict__ c, int S) {
  const int b = blockIdx.x >> 4, h = blockIdx.x & 15;
  const int lane = threadIdx.x;
  float carry = 0.f;
  for (int s0 = 0; s0 < S; s0 += 64) {
    float v = c[(size_t)(b * S + s0 + lane) * 16 + h];
    for (int off = 1; off < 64; off <<= 1) {
      float t = __shfl_up(v, off, 64);
      if (lane >= off) v += t;
    }
    v += carry;
    c[(size_t)(b * S + s0 + lane) * 16 + h] = v;
    carry = __shfl(v, 63, 64);
  }
}

// ---------------------------------------------------------------------------
// V^T prep: qkvb V-part (token-major) -> vtg[(b,h,d), s] bf16
// ---------------------------------------------------------------------------
__global__ __launch_bounds__(256) void vtrans(
    const u16* __restrict__ qkvb, u16* __restrict__ vtg) {
  __shared__ u16 t[32][33];
  const int bh = blockIdx.z, b = bh >> 4, h = bh & 15;
  const int s0 = blockIdx.x * 32, d0 = blockIdx.y * 32;
  const int tx = threadIdx.x & 31, ty = threadIdx.x >> 5;
  for (int i = ty; i < 32; i += 8)
    t[i][tx] = qkvb[(size_t)(b * 2048 + s0 + i) * 3072 + 2048 + h * 64 + d0 + tx];
  __syncthreads();
  for (int i = ty; i < 32; i += 8)
    vtg[(size_t)(bh * 64 + d0 + i) * 2048 + s0 + tx] = t[tx][i];
}

// ---------------------------------------------------------------------------
// MFMA flash attention with forget-gate decay bias.
// Grid (S/64, B*H), 256 threads = 4 waves; wave w owns q-rows [w*16, w*16+16).
// Q/K row-major bf16 LDS (stride 72: 2-way conflicts = free), V^T staged from
// vtg, P round-trips per-wave-private LDS. 64-key tiles.
// ---------------------------------------------------------------------------
#define FS 72

__global__ __launch_bounds__(256) void fattn(
    const u16* __restrict__ qkvb, const u16* __restrict__ vtg,
    const float* __restrict__ c, u16* __restrict__ ctx) {
  __shared__ u16 Qs[64 * FS];
  __shared__ u16 Ks[64 * FS];
  __shared__ u16 Vt[64 * FS];
  __shared__ u16 Ps[64 * FS];
  __shared__ float cjs[64];
  const int S = 2048;
  const int bh = blockIdx.y, b = bh >> 4, h = bh & 15;
  const int i0 = blockIdx.x * 64;
  const int tid = threadIdx.x, wave = tid >> 6, lane = tid & 63;
  const int lr = lane & 15, quad = lane >> 4;
  const int w16 = wave * 16;

  {  // stage Q tile (64x64 bf16)
    const int r = tid >> 2, cc = (tid & 3) * 16;
    const u16* src = qkvb + (size_t)(b * S + i0 + r) * 3072 + h * 64 + cc;
    *(u32x4*)&Qs[r * FS + cc] = *(const u32x4*)src;
    *(u32x4*)&Qs[r * FS + cc + 8] = *(const u32x4*)(src + 8);
  }
  float ci[4], m_[4], l_[4], alpha[4];
  f32x4 o_[4];
  for (int r = 0; r < 4; ++r) {
    ci[r] = c[(size_t)(b * S + i0 + w16 + quad * 4 + r) * 16 + h];
    m_[r] = -INFINITY;
    l_[r] = 0.f;
  }
  for (int dt = 0; dt < 4; ++dt) o_[dt] = (f32x4){0.f, 0.f, 0.f, 0.f};

  const int ntiles = blockIdx.x + 1;
  for (int jt = 0; jt < ntiles; ++jt) {
    const int j0 = jt * 64;
    __syncthreads();
    {  // stage K (row-major) and V^T
      const int r = tid >> 2, cc = (tid & 3) * 16;
      const u16* ks = qkvb + (size_t)(b * S + j0 + r) * 3072 + 1024 + h * 64 + cc;
      *(u32x4*)&Ks[r * FS + cc] = *(const u32x4*)ks;
      *(u32x4*)&Ks[r * FS + cc + 8] = *(const u32x4*)(ks + 8);
      const u16* vs = vtg + (size_t)(bh * 64 + r) * 2048 + j0 + cc;
      *(u32x4*)&Vt[r * FS + cc] = *(const u32x4*)vs;
      *(u32x4*)&Vt[r * FS + cc + 8] = *(const u32x4*)(vs + 8);
      if (tid < 64) cjs[tid] = c[(size_t)(b * S + j0 + tid) * 16 + h];
    }
    __syncthreads();

    // scores: S[i][j] for wave's 16 rows x 64 keys
    bf16x8 aq0 = *(const bf16x8*)&Qs[(w16 + lr) * FS + quad * 8];
    bf16x8 aq1 = *(const bf16x8*)&Qs[(w16 + lr) * FS + 32 + quad * 8];
    f32x4 sc[4];
    for (int nt = 0; nt < 4; ++nt) {
      bf16x8 bk0 = *(const bf16x8*)&Ks[(nt * 16 + lr) * FS + quad * 8];
      bf16x8 bk1 = *(const bf16x8*)&Ks[(nt * 16 + lr) * FS + 32 + quad * 8];
      f32x4 z = {0.f, 0.f, 0.f, 0.f};
      z = __builtin_amdgcn_mfma_f32_16x16x32_bf16(aq0, bk0, z, 0, 0, 0);
      z = __builtin_amdgcn_mfma_f32_16x16x32_bf16(aq1, bk1, z, 0, 0, 0);
      sc[nt] = z;
    }
    const bool diag = (jt == (int)blockIdx.x);
    for (int r = 0; r < 4; ++r) {
      const int i = i0 + w16 + quad * 4 + r;
      float lg[4], mrow = -INFINITY;
      for (int nt = 0; nt < 4; ++nt) {
        const int j = j0 + nt * 16 + lr;
        float v = sc[nt][r] * 0.125f + ci[r] - cjs[nt * 16 + lr];
        if (diag && (j > i)) v = -INFINITY;
        lg[nt] = v;
        mrow = fmaxf(mrow, v);
      }
      for (int off = 1; off < 16; off <<= 1)
        mrow = fmaxf(mrow, __shfl_xor(mrow, off, 64));
      const float mn = fmaxf(m_[r], mrow);
      alpha[r] = __expf(m_[r] - mn);
      m_[r] = mn;
      float rs = 0.f;
      for (int nt = 0; nt < 4; ++nt) {
        const float p = __expf(lg[nt] - mn);
        Ps[(w16 + quad * 4 + r) * FS + nt * 16 + lr] = f2bf(p);
        rs += p;
      }
      for (int off = 1; off < 16; off <<= 1) rs += __shfl_xor(rs, off, 64);
      l_[r] = l_[r] * alpha[r] + rs;
    }
    // make this wave's P writes visible to its own b128 reads
    asm volatile("s_waitcnt lgkmcnt(0)" ::: "memory");
    for (int dt = 0; dt < 4; ++dt)
      for (int r = 0; r < 4; ++r) o_[dt][r] *= alpha[r];
    bf16x8 ap0 = *(const bf16x8*)&Ps[(w16 + lr) * FS + quad * 8];
    bf16x8 ap1 = *(const bf16x8*)&Ps[(w16 + lr) * FS + 32 + quad * 8];
    for (int dt = 0; dt < 4; ++dt) {
      bf16x8 bv0 = *(const bf16x8*)&Vt[(dt * 16 + lr) * FS + quad * 8];
      bf16x8 bv1 = *(const bf16x8*)&Vt[(dt * 16 + lr) * FS + 32 + quad * 8];
      o_[dt] = __builtin_amdgcn_mfma_f32_16x16x32_bf16(ap0, bv0, o_[dt], 0, 0, 0);
      o_[dt] = __builtin_amdgcn_mfma_f32_16x16x32_bf16(ap1, bv1, o_[dt], 0, 0, 0);
    }
  }
  for (int r = 0; r < 4; ++r) {
    const float inv = 1.0f / l_[r];
    const size_t base = (size_t)(b * S + i0 + w16 + quad * 4 + r) * 1024 + h * 64;
    for (int dt = 0; dt < 4; ++dt)
      ctx[base + dt * 16 + lr] = f2bf(o_[dt][r] * inv);
  }
}

// ---------------------------------------------------------------------------
extern "C" void kernel_launch(void* const* d_in, const int* in_sizes, int n_in,
                              void* d_out, int out_size, void* d_ws, size_t ws_size,
                              hipStream_t stream) {
  const float* x    = (const float*)d_in[0];
  const float* ln1g = (const float*)d_in[1];
  const float* ln1b = (const float*)d_in[2];
  const float* wq   = (const float*)d_in[3];
  const float* bq   = (const float*)d_in[4];
  const float* wk   = (const float*)d_in[5];
  const float* bk   = (const float*)d_in[6];
  const float* wv   = (const float*)d_in[7];
  const float* bv   = (const float*)d_in[8];
  const float* wo   = (const float*)d_in[9];
  const float* bo   = (const float*)d_in[10];
  const float* wf   = (const float*)d_in[11];
  const float* bfv  = (const float*)d_in[12];
  const float* ln2g = (const float*)d_in[13];
  const float* ln2b = (const float*)d_in[14];
  const float* w1   = (const float*)d_in[15];
  const float* b1   = (const float*)d_in[16];
  const float* w2   = (const float*)d_in[17];
  const float* b2   = (const float*)d_in[18];
  float* out = (float*)d_out;

  char* ws = (char*)d_ws;
  const size_t MB = 1024 * 1024;
  u16*   wqkvT = (u16*)(ws + 0 * MB);        // 3072x1024 bf16 (6 MB)
  u16*   woT   = (u16*)(ws + 6 * MB);        // 1024x1024 bf16
  u16*   w1T   = (u16*)(ws + 8 * MB);        // 4096x1024 bf16
  u16*   w2T   = (u16*)(ws + 16 * MB);       // 1024x4096 bf16
  u16*   wfT   = (u16*)(ws + 24 * MB);       // 16x1024 bf16
  float* bqkv  = (float*)(ws + 24 * MB + 65536);  // 3072 fp32
  u16*   hbuf  = (u16*)(ws + 25 * MB);       // 4096x1024 bf16
  u16*   ctx   = (u16*)(ws + 33 * MB);       // 4096x1024 bf16
  u16*   qkvb  = (u16*)(ws + 41 * MB);       // 4096x3072 bf16 (24 MB)
  u16*   vtg   = (u16*)(ws + 65 * MB);       // (32*64)x2048 bf16 (8 MB)
  float* cb    = (float*)(ws + 73 * MB);     // 4096x16 fp32
  u16*   act1  = (u16*)(ws + 74 * MB);       // 4096x4096 bf16 (32 MB)

  dim3 blk(256);
  // weight prep
  transpose_cast<<<dim3(32, 32), blk, 0, stream>>>(wq, wqkvT, 1024, 1024);
  transpose_cast<<<dim3(32, 32), blk, 0, stream>>>(wk, wqkvT + 1024 * 1024, 1024, 1024);
  transpose_cast<<<dim3(32, 32), blk, 0, stream>>>(wv, wqkvT + 2 * 1024 * 1024, 1024, 1024);
  transpose_cast<<<dim3(32, 32), blk, 0, stream>>>(wo, woT, 1024, 1024);
  transpose_cast<<<dim3(128, 32), blk, 0, stream>>>(w1, w1T, 1024, 4096);
  transpose_cast<<<dim3(32, 128), blk, 0, stream>>>(w2, w2T, 4096, 1024);
  transpose_cast<<<dim3(1, 32), blk, 0, stream>>>(wf, wfT, 1024, 16);
  pack3<<<12, blk, 0, stream>>>(bq, bk, bv, bqkv);
  // LN1
  ln_kernel<<<4096, blk, 0, stream>>>(x, ln1g, ln1b, hbuf);
  // fused QKV projection -> bf16 (4096 x 3072)
  gemm_bt<<<dim3(24, 32), blk, 0, stream>>>(hbuf, wqkvT, bqkv, nullptr, qkvb,
                                            4096, 3072, 1024, 3);
  // forget gate
  logf_kernel<<<4096, dim3(64), 0, stream>>>(hbuf, wfT, bfv, cb);
  cumsum_kernel<<<32, dim3(64), 0, stream>>>(cb, 2048);
  // V^T prep + attention
  vtrans<<<dim3(64, 2, 32), blk, 0, stream>>>(qkvb, vtg);
  fattn<<<dim3(32, 32), blk, 0, stream>>>(qkvb, vtg, cb, ctx);
  // out projection + residual -> d_out
  gemm_bt<<<dim3(8, 32), blk, 0, stream>>>(ctx, woT, bo, x, out, 4096, 1024, 1024, 1);
  // LN2
  ln_kernel<<<4096, blk, 0, stream>>>(out, ln2g, ln2b, hbuf);
  // MLP
  gemm_bt<<<dim3(32, 32), blk, 0, stream>>>(hbuf, w1T, b1, nullptr, act1,
                                            4096, 4096, 1024, 2);
  gemm_bt<<<dim3(8, 32), blk, 0, stream>>>(act1, w2T, b2, out, out,
                                           4096, 1024, 4096, 1);
}

// Round 3
// 603.157 us; speedup vs baseline: 4.7835x; 3.7019x over previous
//
#include <hip/hip_runtime.h>
#include <hip/hip_bf16.h>
#include <math.h>

typedef unsigned short u16;
typedef unsigned int u32;
typedef __bf16 bf16x8 __attribute__((ext_vector_type(8)));
typedef float f32x4 __attribute__((ext_vector_type(4)));
typedef u32 u32x4 __attribute__((ext_vector_type(4)));

__device__ __forceinline__ u16 f2bf(float f) {
  __hip_bfloat16 h = __float2bfloat16(f);
  return *reinterpret_cast<u16*>(&h);
}
__device__ __forceinline__ float bf2f(u16 u) {
  return __uint_as_float(((u32)u) << 16);
}

// async global->LDS, 16B per lane; LDS dest = wave-uniform base + lane*16
#define GLL(gp, lp)                                                     \
  __builtin_amdgcn_global_load_lds(                                     \
      (const __attribute__((address_space(1))) void*)(gp),              \
      (__attribute__((address_space(3))) void*)(lp), 16, 0, 0)

// ---------------------------------------------------------------------------
// Transpose + cast fp32 (R x C) -> bf16 (C x R)
// ---------------------------------------------------------------------------
__global__ __launch_bounds__(256) void transpose_cast(
    const float* __restrict__ in, u16* __restrict__ out, int R, int C) {
  __shared__ float tile[32][33];
  int c0 = blockIdx.x * 32, r0 = blockIdx.y * 32;
  int tx = threadIdx.x & 31, ty = threadIdx.x >> 5;
  for (int i = ty; i < 32; i += 8) {
    int r = r0 + i, c = c0 + tx;
    if (r < R && c < C) tile[i][tx] = in[(size_t)r * C + c];
  }
  __syncthreads();
  for (int i = ty; i < 32; i += 8) {
    int c = c0 + i, r = r0 + tx;
    if (c < C && r < R) out[(size_t)c * R + r] = f2bf(tile[tx][i]);
  }
}

// pack bq,bk,bv -> 3072-float bias
__global__ __launch_bounds__(256) void pack3(
    const float* __restrict__ a, const float* __restrict__ b,
    const float* __restrict__ c, float* __restrict__ o) {
  int t = blockIdx.x * 256 + threadIdx.x;
  if (t < 1024) o[t] = a[t];
  else if (t < 2048) o[t] = b[t - 1024];
  else if (t < 3072) o[t] = c[t - 2048];
}

// ---------------------------------------------------------------------------
// LayerNorm over last dim (1024), fp32 in -> bf16 out. One block per row.
// ---------------------------------------------------------------------------
__global__ __launch_bounds__(256) void ln_kernel(
    const float* __restrict__ x, const float* __restrict__ g,
    const float* __restrict__ bb, u16* __restrict__ out) {
  __shared__ float red[8];
  const int row = blockIdx.x;
  const float* xr = x + (size_t)row * 1024;
  f32x4 v = *(const f32x4*)(xr + threadIdx.x * 4);
  float s = v[0] + v[1] + v[2] + v[3];
  #pragma unroll
  for (int off = 32; off > 0; off >>= 1) s += __shfl_xor(s, off, 64);
  if ((threadIdx.x & 63) == 0) red[threadIdx.x >> 6] = s;
  __syncthreads();
  float mu = (red[0] + red[1] + red[2] + red[3]) * (1.0f / 1024.0f);
  f32x4 d;
  d[0] = v[0] - mu; d[1] = v[1] - mu; d[2] = v[2] - mu; d[3] = v[3] - mu;
  float sq = d[0]*d[0] + d[1]*d[1] + d[2]*d[2] + d[3]*d[3];
  #pragma unroll
  for (int off = 32; off > 0; off >>= 1) sq += __shfl_xor(sq, off, 64);
  if ((threadIdx.x & 63) == 0) red[4 + (threadIdx.x >> 6)] = sq;
  __syncthreads();
  float var = (red[4] + red[5] + red[6] + red[7]) * (1.0f / 1024.0f);
  float rstd = rsqrtf(var + 1e-5f);
  int cb = threadIdx.x * 4;
  #pragma unroll
  for (int e = 0; e < 4; ++e)
    out[(size_t)row * 1024 + cb + e] = f2bf(d[e] * rstd * g[cb + e] + bb[cb + e]);
}

// ---------------------------------------------------------------------------
// bf16 MFMA GEMM with global_load_lds width-16 staging (m97 structure).
// C[M,N] = A[M,K] * Bt[N,K]^T + bias. 128x128 tile, BK=32, 4 waves 2x2,
// each wave 4x4 of 16x16x32.
// mode 0: fp32 out          mode 1: fp32 out + res
// mode 2: bf16 out = gelu   mode 3: bf16 out
// NOTE: every constant-trip loop is #pragma unroll'd. Round-2 post-mortem:
// without it, acc/af/bfr stayed un-promoted (VGPR_Count=28) and spilled to
// scratch -> 3.4 GB HBM traffic/dispatch, 52 TF. Registers or bust.
// ---------------------------------------------------------------------------
__global__ __launch_bounds__(256) void gemm_bt(
    const u16* __restrict__ A, const u16* __restrict__ Bt,
    const float* __restrict__ bias, const float* __restrict__ res,
    void* __restrict__ outp, int M, int N, int K, int mode) {
  __shared__ u16 As[128 * 32];
  __shared__ u16 Bs[128 * 32];
  const int tid = threadIdx.x;
  const int m0 = blockIdx.y * 128, n0 = blockIdx.x * 128;
  const int wave = tid >> 6, lane = tid & 63;
  const int wm = (wave >> 1) * 64, wn = (wave & 1) * 64;
  const int lr = lane & 15, quad = lane >> 4;
  // staging: 8 groups of 16 rows (1024B each); wave w stages groups 2w, 2w+1
  const int g0 = wave * 2;
  const int srow0 = g0 * 16 + (lane >> 2);
  const int scol = (lane & 3) * 8;
  const u16* Ag0 = A + (size_t)(m0 + srow0) * K + scol;
  const u16* Ag1 = A + (size_t)(m0 + srow0 + 16) * K + scol;
  const u16* Bg0 = Bt + (size_t)(n0 + srow0) * K + scol;
  const u16* Bg1 = Bt + (size_t)(n0 + srow0 + 16) * K + scol;
  u16* Al0 = As + g0 * 512;
  u16* Al1 = As + (g0 + 1) * 512;
  u16* Bl0 = Bs + g0 * 512;
  u16* Bl1 = Bs + (g0 + 1) * 512;

  f32x4 acc[4][4] = {};

  for (int k0 = 0; k0 < K; k0 += 32) {
    GLL(Ag0 + k0, Al0);
    GLL(Ag1 + k0, Al1);
    GLL(Bg0 + k0, Bl0);
    GLL(Bg1 + k0, Bl1);
    __syncthreads();
    bf16x8 af[4], bfr[4];
    #pragma unroll
    for (int t = 0; t < 4; ++t) {
      af[t]  = *(const bf16x8*)&As[(wm + t * 16 + lr) * 32 + quad * 8];
      bfr[t] = *(const bf16x8*)&Bs[(wn + t * 16 + lr) * 32 + quad * 8];
    }
    #pragma unroll
    for (int mt = 0; mt < 4; ++mt)
      #pragma unroll
      for (int nt = 0; nt < 4; ++nt)
        acc[mt][nt] = __builtin_amdgcn_mfma_f32_16x16x32_bf16(
            af[mt], bfr[nt], acc[mt][nt], 0, 0, 0);
    __syncthreads();
  }

  #pragma unroll
  for (int mt = 0; mt < 4; ++mt) {
    #pragma unroll
    for (int nt = 0; nt < 4; ++nt) {
      const int col = n0 + wn + nt * 16 + lr;
      const float bvv = bias[col];
      #pragma unroll
      for (int rr = 0; rr < 4; ++rr) {
        const int row = m0 + wm + mt * 16 + quad * 4 + rr;
        const size_t idx = (size_t)row * N + col;
        float v = acc[mt][nt][rr] + bvv;
        if (mode == 0) {
          ((float*)outp)[idx] = v;
        } else if (mode == 1) {
          ((float*)outp)[idx] = v + res[idx];
        } else if (mode == 2) {
          float gl = 0.5f * v * (1.0f + erff(v * 0.70710678118654752f));
          ((u16*)outp)[idx] = f2bf(gl);
        } else {
          ((u16*)outp)[idx] = f2bf(v);
        }
      }
    }
  }
}

// ---------------------------------------------------------------------------
// logf = log_sigmoid(h @ wf + bf), one wave per row. wfT is (16 x 1024) bf16.
// ---------------------------------------------------------------------------
__global__ __launch_bounds__(64) void logf_kernel(
    const u16* __restrict__ h, const u16* __restrict__ wfT,
    const float* __restrict__ bfv, float* __restrict__ c) {
  const int row = blockIdx.x;
  const int lane = threadIdx.x;
  float acc[16];
  #pragma unroll
  for (int n = 0; n < 16; ++n) acc[n] = 0.f;
  for (int t = 0; t < 16; ++t) {
    int kidx = t * 64 + lane;
    float hv = bf2f(h[(size_t)row * 1024 + kidx]);
    #pragma unroll
    for (int n = 0; n < 16; ++n)
      acc[n] += hv * bf2f(wfT[n * 1024 + kidx]);
  }
  float z = 0.f;
  #pragma unroll
  for (int n = 0; n < 16; ++n) {
    float r = acc[n];
    #pragma unroll
    for (int off = 1; off < 64; off <<= 1) r += __shfl_xor(r, off, 64);
    if (lane == n) z = r;
  }
  if (lane < 16) {
    z += bfv[lane];
    float lf = (z >= 0.f) ? -log1pf(expf(-z)) : (z - log1pf(expf(z)));
    c[(size_t)row * 16 + lane] = lf;
  }
}

__global__ __launch_bounds__(64) void cumsum_kernel(float* __restrict__ c, int S) {
  const int b = blockIdx.x >> 4, h = blockIdx.x & 15;
  const int lane = threadIdx.x;
  float carry = 0.f;
  for (int s0 = 0; s0 < S; s0 += 64) {
    float v = c[(size_t)(b * S + s0 + lane) * 16 + h];
    #pragma unroll
    for (int off = 1; off < 64; off <<= 1) {
      float t = __shfl_up(v, off, 64);
      if (lane >= off) v += t;
    }
    v += carry;
    c[(size_t)(b * S + s0 + lane) * 16 + h] = v;
    carry = __shfl(v, 63, 64);
  }
}

// ---------------------------------------------------------------------------
// V^T prep: qkvb V-part (token-major) -> vtg[(b,h,d), s] bf16
// ---------------------------------------------------------------------------
__global__ __launch_bounds__(256) void vtrans(
    const u16* __restrict__ qkvb, u16* __restrict__ vtg) {
  __shared__ u16 t[32][33];
  const int bh = blockIdx.z, b = bh >> 4, h = bh & 15;
  const int s0 = blockIdx.x * 32, d0 = blockIdx.y * 32;
  const int tx = threadIdx.x & 31, ty = threadIdx.x >> 5;
  for (int i = ty; i < 32; i += 8)
    t[i][tx] = qkvb[(size_t)(b * 2048 + s0 + i) * 3072 + 2048 + h * 64 + d0 + tx];
  __syncthreads();
  for (int i = ty; i < 32; i += 8)
    vtg[(size_t)(bh * 64 + d0 + i) * 2048 + s0 + tx] = t[tx][i];
}

// ---------------------------------------------------------------------------
// MFMA flash attention with forget-gate decay bias.
// Grid (S/64, B*H), 256 threads = 4 waves; wave w owns q-rows [w*16, w*16+16).
// ---------------------------------------------------------------------------
#define FS 72

__global__ __launch_bounds__(256) void fattn(
    const u16* __restrict__ qkvb, const u16* __restrict__ vtg,
    const float* __restrict__ c, u16* __restrict__ ctx) {
  __shared__ u16 Qs[64 * FS];
  __shared__ u16 Ks[64 * FS];
  __shared__ u16 Vt[64 * FS];
  __shared__ u16 Ps[64 * FS];
  __shared__ float cjs[64];
  const int S = 2048;
  const int bh = blockIdx.y, b = bh >> 4, h = bh & 15;
  const int i0 = blockIdx.x * 64;
  const int tid = threadIdx.x, wave = tid >> 6, lane = tid & 63;
  const int lr = lane & 15, quad = lane >> 4;
  const int w16 = wave * 16;

  {  // stage Q tile (64x64 bf16)
    const int r = tid >> 2, cc = (tid & 3) * 16;
    const u16* src = qkvb + (size_t)(b * S + i0 + r) * 3072 + h * 64 + cc;
    *(u32x4*)&Qs[r * FS + cc] = *(const u32x4*)src;
    *(u32x4*)&Qs[r * FS + cc + 8] = *(const u32x4*)(src + 8);
  }
  float ci[4], m_[4], l_[4], alpha[4];
  f32x4 o_[4];
  #pragma unroll
  for (int r = 0; r < 4; ++r) {
    ci[r] = c[(size_t)(b * S + i0 + w16 + quad * 4 + r) * 16 + h];
    m_[r] = -INFINITY;
    l_[r] = 0.f;
  }
  #pragma unroll
  for (int dt = 0; dt < 4; ++dt) o_[dt] = (f32x4){0.f, 0.f, 0.f, 0.f};

  const int ntiles = blockIdx.x + 1;
  for (int jt = 0; jt < ntiles; ++jt) {
    const int j0 = jt * 64;
    __syncthreads();
    {  // stage K (row-major) and V^T
      const int r = tid >> 2, cc = (tid & 3) * 16;
      const u16* ks = qkvb + (size_t)(b * S + j0 + r) * 3072 + 1024 + h * 64 + cc;
      *(u32x4*)&Ks[r * FS + cc] = *(const u32x4*)ks;
      *(u32x4*)&Ks[r * FS + cc + 8] = *(const u32x4*)(ks + 8);
      const u16* vs = vtg + (size_t)(bh * 64 + r) * 2048 + j0 + cc;
      *(u32x4*)&Vt[r * FS + cc] = *(const u32x4*)vs;
      *(u32x4*)&Vt[r * FS + cc + 8] = *(const u32x4*)(vs + 8);
      if (tid < 64) cjs[tid] = c[(size_t)(b * S + j0 + tid) * 16 + h];
    }
    __syncthreads();

    // scores: S[i][j] for wave's 16 rows x 64 keys
    bf16x8 aq0 = *(const bf16x8*)&Qs[(w16 + lr) * FS + quad * 8];
    bf16x8 aq1 = *(const bf16x8*)&Qs[(w16 + lr) * FS + 32 + quad * 8];
    f32x4 sc[4];
    #pragma unroll
    for (int nt = 0; nt < 4; ++nt) {
      bf16x8 bk0 = *(const bf16x8*)&Ks[(nt * 16 + lr) * FS + quad * 8];
      bf16x8 bk1 = *(const bf16x8*)&Ks[(nt * 16 + lr) * FS + 32 + quad * 8];
      f32x4 z = {0.f, 0.f, 0.f, 0.f};
      z = __builtin_amdgcn_mfma_f32_16x16x32_bf16(aq0, bk0, z, 0, 0, 0);
      z = __builtin_amdgcn_mfma_f32_16x16x32_bf16(aq1, bk1, z, 0, 0, 0);
      sc[nt] = z;
    }
    const bool diag = (jt == (int)blockIdx.x);
    #pragma unroll
    for (int r = 0; r < 4; ++r) {
      const int i = i0 + w16 + quad * 4 + r;
      float lg[4], mrow = -INFINITY;
      #pragma unroll
      for (int nt = 0; nt < 4; ++nt) {
        const int j = j0 + nt * 16 + lr;
        float v = sc[nt][r] * 0.125f + ci[r] - cjs[nt * 16 + lr];
        if (diag && (j > i)) v = -INFINITY;
        lg[nt] = v;
        mrow = fmaxf(mrow, v);
      }
      #pragma unroll
      for (int off = 1; off < 16; off <<= 1)
        mrow = fmaxf(mrow, __shfl_xor(mrow, off, 64));
      const float mn = fmaxf(m_[r], mrow);
      alpha[r] = __expf(m_[r] - mn);
      m_[r] = mn;
      float rs = 0.f;
      #pragma unroll
      for (int nt = 0; nt < 4; ++nt) {
        const float p = __expf(lg[nt] - mn);
        Ps[(w16 + quad * 4 + r) * FS + nt * 16 + lr] = f2bf(p);
        rs += p;
      }
      #pragma unroll
      for (int off = 1; off < 16; off <<= 1) rs += __shfl_xor(rs, off, 64);
      l_[r] = l_[r] * alpha[r] + rs;
    }
    // make this wave's P writes visible to its own b128 reads
    asm volatile("s_waitcnt lgkmcnt(0)" ::: "memory");
    #pragma unroll
    for (int dt = 0; dt < 4; ++dt)
      #pragma unroll
      for (int r = 0; r < 4; ++r) o_[dt][r] *= alpha[r];
    bf16x8 ap0 = *(const bf16x8*)&Ps[(w16 + lr) * FS + quad * 8];
    bf16x8 ap1 = *(const bf16x8*)&Ps[(w16 + lr) * FS + 32 + quad * 8];
    #pragma unroll
    for (int dt = 0; dt < 4; ++dt) {
      bf16x8 bv0 = *(const bf16x8*)&Vt[(dt * 16 + lr) * FS + quad * 8];
      bf16x8 bv1 = *(const bf16x8*)&Vt[(dt * 16 + lr) * FS + 32 + quad * 8];
      o_[dt] = __builtin_amdgcn_mfma_f32_16x16x32_bf16(ap0, bv0, o_[dt], 0, 0, 0);
      o_[dt] = __builtin_amdgcn_mfma_f32_16x16x32_bf16(ap1, bv1, o_[dt], 0, 0, 0);
    }
  }
  #pragma unroll
  for (int r = 0; r < 4; ++r) {
    const float inv = 1.0f / l_[r];
    const size_t base = (size_t)(b * S + i0 + w16 + quad * 4 + r) * 1024 + h * 64;
    #pragma unroll
    for (int dt = 0; dt < 4; ++dt)
      ctx[base + dt * 16 + lr] = f2bf(o_[dt][r] * inv);
  }
}

// ---------------------------------------------------------------------------
extern "C" void kernel_launch(void* const* d_in, const int* in_sizes, int n_in,
                              void* d_out, int out_size, void* d_ws, size_t ws_size,
                              hipStream_t stream) {
  const float* x    = (const float*)d_in[0];
  const float* ln1g = (const float*)d_in[1];
  const float* ln1b = (const float*)d_in[2];
  const float* wq   = (const float*)d_in[3];
  const float* bq   = (const float*)d_in[4];
  const float* wk   = (const float*)d_in[5];
  const float* bk   = (const float*)d_in[6];
  const float* wv   = (const float*)d_in[7];
  const float* bv   = (const float*)d_in[8];
  const float* wo   = (const float*)d_in[9];
  const float* bo   = (const float*)d_in[10];
  const float* wf   = (const float*)d_in[11];
  const float* bfv  = (const float*)d_in[12];
  const float* ln2g = (const float*)d_in[13];
  const float* ln2b = (const float*)d_in[14];
  const float* w1   = (const float*)d_in[15];
  const float* b1   = (const float*)d_in[16];
  const float* w2   = (const float*)d_in[17];
  const float* b2   = (const float*)d_in[18];
  float* out = (float*)d_out;

  char* ws = (char*)d_ws;
  const size_t MB = 1024 * 1024;
  u16*   wqkvT = (u16*)(ws + 0 * MB);        // 3072x1024 bf16 (6 MB)
  u16*   woT   = (u16*)(ws + 6 * MB);        // 1024x1024 bf16
  u16*   w1T   = (u16*)(ws + 8 * MB);        // 4096x1024 bf16
  u16*   w2T   = (u16*)(ws + 16 * MB);       // 1024x4096 bf16
  u16*   wfT   = (u16*)(ws + 24 * MB);       // 16x1024 bf16
  float* bqkv  = (float*)(ws + 24 * MB + 65536);  // 3072 fp32
  u16*   hbuf  = (u16*)(ws + 25 * MB);       // 4096x1024 bf16
  u16*   ctx   = (u16*)(ws + 33 * MB);       // 4096x1024 bf16
  u16*   qkvb  = (u16*)(ws + 41 * MB);       // 4096x3072 bf16 (24 MB)
  u16*   vtg   = (u16*)(ws + 65 * MB);       // (32*64)x2048 bf16 (8 MB)
  float* cb    = (float*)(ws + 73 * MB);     // 4096x16 fp32
  u16*   act1  = (u16*)(ws + 74 * MB);       // 4096x4096 bf16 (32 MB)

  dim3 blk(256);
  // weight prep
  transpose_cast<<<dim3(32, 32), blk, 0, stream>>>(wq, wqkvT, 1024, 1024);
  transpose_cast<<<dim3(32, 32), blk, 0, stream>>>(wk, wqkvT + 1024 * 1024, 1024, 1024);
  transpose_cast<<<dim3(32, 32), blk, 0, stream>>>(wv, wqkvT + 2 * 1024 * 1024, 1024, 1024);
  transpose_cast<<<dim3(32, 32), blk, 0, stream>>>(wo, woT, 1024, 1024);
  transpose_cast<<<dim3(128, 32), blk, 0, stream>>>(w1, w1T, 1024, 4096);
  transpose_cast<<<dim3(32, 128), blk, 0, stream>>>(w2, w2T, 4096, 1024);
  transpose_cast<<<dim3(1, 32), blk, 0, stream>>>(wf, wfT, 1024, 16);
  pack3<<<12, blk, 0, stream>>>(bq, bk, bv, bqkv);
  // LN1
  ln_kernel<<<4096, blk, 0, stream>>>(x, ln1g, ln1b, hbuf);
  // fused QKV projection -> bf16 (4096 x 3072)
  gemm_bt<<<dim3(24, 32), blk, 0, stream>>>(hbuf, wqkvT, bqkv, nullptr, qkvb,
                                            4096, 3072, 1024, 3);
  // forget gate
  logf_kernel<<<4096, dim3(64), 0, stream>>>(hbuf, wfT, bfv, cb);
  cumsum_kernel<<<32, dim3(64), 0, stream>>>(cb, 2048);
  // V^T prep + attention
  vtrans<<<dim3(64, 2, 32), blk, 0, stream>>>(qkvb, vtg);
  fattn<<<dim3(32, 32), blk, 0, stream>>>(qkvb, vtg, cb, ctx);
  // out projection + residual -> d_out
  gemm_bt<<<dim3(8, 32), blk, 0, stream>>>(ctx, woT, bo, x, out, 4096, 1024, 1024, 1);
  // LN2
  ln_kernel<<<4096, blk, 0, stream>>>(out, ln2g, ln2b, hbuf);
  // MLP
  gemm_bt<<<dim3(32, 32), blk, 0, stream>>>(hbuf, w1T, b1, nullptr, act1,
                                            4096, 4096, 1024, 2);
  gemm_bt<<<dim3(8, 32), blk, 0, stream>>>(act1, w2T, b2, out, out,
                                           4096, 1024, 4096, 1);
}

// Round 5
// 568.433 us; speedup vs baseline: 5.0757x; 1.0611x over previous
//
#include <hip/hip_runtime.h>
#include <hip/hip_bf16.h>
#include <math.h>

typedef unsigned short u16;
typedef unsigned int u32;
typedef __bf16 bf16x8 __attribute__((ext_vector_type(8)));
typedef float f32x4 __attribute__((ext_vector_type(4)));
typedef u32 u32x4 __attribute__((ext_vector_type(4)));

__device__ __forceinline__ u16 f2bf(float f) {
  __hip_bfloat16 h = __float2bfloat16(f);
  return *reinterpret_cast<u16*>(&h);
}
__device__ __forceinline__ float bf2f(u16 u) {
  return __uint_as_float(((u32)u) << 16);
}

// async global->LDS, 16B per lane; LDS dest = wave-uniform base + lane*16
#define GLL(gp, lp)                                                     \
  __builtin_amdgcn_global_load_lds(                                     \
      (const __attribute__((address_space(1))) void*)(gp),              \
      (__attribute__((address_space(3))) void*)(lp), 16, 0, 0)

// ---------------------------------------------------------------------------
// Transpose + cast fp32 (R x C) -> bf16 (C x R)
// ---------------------------------------------------------------------------
__global__ __launch_bounds__(256) void transpose_cast(
    const float* __restrict__ in, u16* __restrict__ out, int R, int C) {
  __shared__ float tile[32][33];
  int c0 = blockIdx.x * 32, r0 = blockIdx.y * 32;
  int tx = threadIdx.x & 31, ty = threadIdx.x >> 5;
  for (int i = ty; i < 32; i += 8) {
    int r = r0 + i, c = c0 + tx;
    if (r < R && c < C) tile[i][tx] = in[(size_t)r * C + c];
  }
  __syncthreads();
  for (int i = ty; i < 32; i += 8) {
    int c = c0 + i, r = r0 + tx;
    if (c < C && r < R) out[(size_t)c * R + r] = f2bf(tile[tx][i]);
  }
}

// pack bq,bk,bv -> 3072-float bias; ALSO zeroes the fattn work-steal counter
// (runs on-stream before fattn; avoids hipMemsetAsync in kernel_launch, which
// was the only runtime-API change in the round that failed to bench)
__global__ __launch_bounds__(256) void pack3(
    const float* __restrict__ a, const float* __restrict__ b,
    const float* __restrict__ c, float* __restrict__ o, u32* __restrict__ ctr) {
  int t = blockIdx.x * 256 + threadIdx.x;
  if (t == 0) *ctr = 0u;
  if (t < 1024) o[t] = a[t];
  else if (t < 2048) o[t] = b[t - 1024];
  else if (t < 3072) o[t] = c[t - 2048];
}

// ---------------------------------------------------------------------------
// LayerNorm over last dim (1024), fp32 in -> bf16 out. One block per row.
// ---------------------------------------------------------------------------
__global__ __launch_bounds__(256) void ln_kernel(
    const float* __restrict__ x, const float* __restrict__ g,
    const float* __restrict__ bb, u16* __restrict__ out) {
  __shared__ float red[8];
  const int row = blockIdx.x;
  const float* xr = x + (size_t)row * 1024;
  f32x4 v = *(const f32x4*)(xr + threadIdx.x * 4);
  float s = v[0] + v[1] + v[2] + v[3];
  #pragma unroll
  for (int off = 32; off > 0; off >>= 1) s += __shfl_xor(s, off, 64);
  if ((threadIdx.x & 63) == 0) red[threadIdx.x >> 6] = s;
  __syncthreads();
  float mu = (red[0] + red[1] + red[2] + red[3]) * (1.0f / 1024.0f);
  f32x4 d;
  d[0] = v[0] - mu; d[1] = v[1] - mu; d[2] = v[2] - mu; d[3] = v[3] - mu;
  float sq = d[0]*d[0] + d[1]*d[1] + d[2]*d[2] + d[3]*d[3];
  #pragma unroll
  for (int off = 32; off > 0; off >>= 1) sq += __shfl_xor(sq, off, 64);
  if ((threadIdx.x & 63) == 0) red[4 + (threadIdx.x >> 6)] = sq;
  __syncthreads();
  float var = (red[4] + red[5] + red[6] + red[7]) * (1.0f / 1024.0f);
  float rstd = rsqrtf(var + 1e-5f);
  int cb = threadIdx.x * 4;
  #pragma unroll
  for (int e = 0; e < 4; ++e)
    out[(size_t)row * 1024 + cb + e] = f2bf(d[e] * rstd * g[cb + e] + bb[cb + e]);
}

// ---------------------------------------------------------------------------
// bf16 MFMA GEMM with global_load_lds width-16 staging (m97 structure).
// C[M,N] = A[M,K] * Bt[N,K]^T + bias. 128x128 tile, BK=32, 4 waves 2x2,
// each wave 4x4 of 16x16x32.
// mode 0: fp32 out          mode 1: fp32 out + res
// mode 2: bf16 out = gelu   mode 3: bf16 out
// NOTE: every constant-trip loop is #pragma unroll'd (round-2 post-mortem:
// without it acc spilled to scratch -> 3.4 GB HBM/dispatch, 52 TF).
// ---------------------------------------------------------------------------
__global__ __launch_bounds__(256) void gemm_bt(
    const u16* __restrict__ A, const u16* __restrict__ Bt,
    const float* __restrict__ bias, const float* __restrict__ res,
    void* __restrict__ outp, int M, int N, int K, int mode) {
  __shared__ u16 As[128 * 32];
  __shared__ u16 Bs[128 * 32];
  const int tid = threadIdx.x;
  const int m0 = blockIdx.y * 128, n0 = blockIdx.x * 128;
  const int wave = tid >> 6, lane = tid & 63;
  const int wm = (wave >> 1) * 64, wn = (wave & 1) * 64;
  const int lr = lane & 15, quad = lane >> 4;
  const int g0 = wave * 2;
  const int srow0 = g0 * 16 + (lane >> 2);
  const int scol = (lane & 3) * 8;
  const u16* Ag0 = A + (size_t)(m0 + srow0) * K + scol;
  const u16* Ag1 = A + (size_t)(m0 + srow0 + 16) * K + scol;
  const u16* Bg0 = Bt + (size_t)(n0 + srow0) * K + scol;
  const u16* Bg1 = Bt + (size_t)(n0 + srow0 + 16) * K + scol;
  u16* Al0 = As + g0 * 512;
  u16* Al1 = As + (g0 + 1) * 512;
  u16* Bl0 = Bs + g0 * 512;
  u16* Bl1 = Bs + (g0 + 1) * 512;

  f32x4 acc[4][4] = {};

  for (int k0 = 0; k0 < K; k0 += 32) {
    GLL(Ag0 + k0, Al0);
    GLL(Ag1 + k0, Al1);
    GLL(Bg0 + k0, Bl0);
    GLL(Bg1 + k0, Bl1);
    __syncthreads();
    bf16x8 af[4], bfr[4];
    #pragma unroll
    for (int t = 0; t < 4; ++t) {
      af[t]  = *(const bf16x8*)&As[(wm + t * 16 + lr) * 32 + quad * 8];
      bfr[t] = *(const bf16x8*)&Bs[(wn + t * 16 + lr) * 32 + quad * 8];
    }
    #pragma unroll
    for (int mt = 0; mt < 4; ++mt)
      #pragma unroll
      for (int nt = 0; nt < 4; ++nt)
        acc[mt][nt] = __builtin_amdgcn_mfma_f32_16x16x32_bf16(
            af[mt], bfr[nt], acc[mt][nt], 0, 0, 0);
    __syncthreads();
  }

  #pragma unroll
  for (int mt = 0; mt < 4; ++mt) {
    #pragma unroll
    for (int nt = 0; nt < 4; ++nt) {
      const int col = n0 + wn + nt * 16 + lr;
      const float bvv = bias[col];
      #pragma unroll
      for (int rr = 0; rr < 4; ++rr) {
        const int row = m0 + wm + mt * 16 + quad * 4 + rr;
        const size_t idx = (size_t)row * N + col;
        float v = acc[mt][nt][rr] + bvv;
        if (mode == 0) {
          ((float*)outp)[idx] = v;
        } else if (mode == 1) {
          ((float*)outp)[idx] = v + res[idx];
        } else if (mode == 2) {
          float gl = 0.5f * v * (1.0f + erff(v * 0.70710678118654752f));
          ((u16*)outp)[idx] = f2bf(gl);
        } else {
          ((u16*)outp)[idx] = f2bf(v);
        }
      }
    }
  }
}

// ---------------------------------------------------------------------------
// logf = log_sigmoid(h @ wf + bf), one wave per row. wfT is (16 x 1024) bf16.
// ---------------------------------------------------------------------------
__global__ __launch_bounds__(64) void logf_kernel(
    const u16* __restrict__ h, const u16* __restrict__ wfT,
    const float* __restrict__ bfv, float* __restrict__ c) {
  const int row = blockIdx.x;
  const int lane = threadIdx.x;
  float acc[16];
  #pragma unroll
  for (int n = 0; n < 16; ++n) acc[n] = 0.f;
  for (int t = 0; t < 16; ++t) {
    int kidx = t * 64 + lane;
    float hv = bf2f(h[(size_t)row * 1024 + kidx]);
    #pragma unroll
    for (int n = 0; n < 16; ++n)
      acc[n] += hv * bf2f(wfT[n * 1024 + kidx]);
  }
  float z = 0.f;
  #pragma unroll
  for (int n = 0; n < 16; ++n) {
    float r = acc[n];
    #pragma unroll
    for (int off = 1; off < 64; off <<= 1) r += __shfl_xor(r, off, 64);
    if (lane == n) z = r;
  }
  if (lane < 16) {
    z += bfv[lane];
    float lf = (z >= 0.f) ? -log1pf(expf(-z)) : (z - log1pf(expf(z)));
    c[(size_t)row * 16 + lane] = lf;
  }
}

__global__ __launch_bounds__(64) void cumsum_kernel(float* __restrict__ c, int S) {
  const int b = blockIdx.x >> 4, h = blockIdx.x & 15;
  const int lane = threadIdx.x;
  float carry = 0.f;
  for (int s0 = 0; s0 < S; s0 += 64) {
    float v = c[(size_t)(b * S + s0 + lane) * 16 + h];
    #pragma unroll
    for (int off = 1; off < 64; off <<= 1) {
      float t = __shfl_up(v, off, 64);
      if (lane >= off) v += t;
    }
    v += carry;
    c[(size_t)(b * S + s0 + lane) * 16 + h] = v;
    carry = __shfl(v, 63, 64);
  }
}

// ---------------------------------------------------------------------------
// V^T prep: qkvb V-part (token-major) -> vtg[(b,h,d), s] bf16
// ---------------------------------------------------------------------------
__global__ __launch_bounds__(256) void vtrans(
    const u16* __restrict__ qkvb, u16* __restrict__ vtg) {
  __shared__ u16 t[32][33];
  const int bh = blockIdx.z, b = bh >> 4, h = bh & 15;
  const int s0 = blockIdx.x * 32, d0 = blockIdx.y * 32;
  const int tx = threadIdx.x & 31, ty = threadIdx.x >> 5;
  for (int i = ty; i < 32; i += 8)
    t[i][tx] = qkvb[(size_t)(b * 2048 + s0 + i) * 3072 + 2048 + h * 64 + d0 + tx];
  __syncthreads();
  for (int i = ty; i < 32; i += 8)
    vtg[(size_t)(bh * 64 + d0 + i) * 2048 + s0 + tx] = t[tx][i];
}

// ---------------------------------------------------------------------------
// MFMA flash attention with forget-gate decay bias. WORK-STEALING version:
// 512 blocks pull (t, bh) items (t = q-tile, descending work order) from a
// global atomic counter -> near-perfect LPT balance regardless of the
// block->CU mapping. (Round-3 post-mortem: static grid had 4x-imbalanced
// co-resident blocks -> critical CU did ~128 tile-iters, occupancy 19%.)
// 256 threads = 4 waves; wave w owns q-rows [w*16, w*16+16) of the tile.
// ---------------------------------------------------------------------------
#define FS 72
#define NITEMS 1024  // 32 q-tiles * 32 bh

__global__ __launch_bounds__(256) void fattn(
    const u16* __restrict__ qkvb, const u16* __restrict__ vtg,
    const float* __restrict__ c, u16* __restrict__ ctx, u32* __restrict__ ctr) {
  __shared__ u16 Qs[64 * FS];
  __shared__ u16 Ks[64 * FS];
  __shared__ u16 Vt[64 * FS];
  __shared__ u16 Ps[64 * FS];
  __shared__ float cjs[64];
  __shared__ u32 sh_item;
  const int S = 2048;
  const int tid = threadIdx.x, wave = tid >> 6, lane = tid & 63;
  const int lr = lane & 15, quad = lane >> 4;
  const int w16 = wave * 16;

  for (;;) {
    if (tid == 0) sh_item = atomicAdd(ctr, 1u);
    // barrier: publishes sh_item AND fences old-item LDS reads from the
    // Q-restage below (all waves are past their last Qs/Ps/Vt read here)
    __syncthreads();
    const u32 item = sh_item;
    if (item >= NITEMS) return;
    const int qt = 31 - (int)(item >> 5);       // descending work
    const int bh = (int)(item & 31), b = bh >> 4, h = bh & 15;
    const int i0 = qt * 64;

    {  // stage Q tile (64x64 bf16)
      const int r = tid >> 2, cc = (tid & 3) * 16;
      const u16* src = qkvb + (size_t)(b * S + i0 + r) * 3072 + h * 64 + cc;
      *(u32x4*)&Qs[r * FS + cc] = *(const u32x4*)src;
      *(u32x4*)&Qs[r * FS + cc + 8] = *(const u32x4*)(src + 8);
    }
    float ci[4], m_[4], l_[4], alpha[4];
    f32x4 o_[4];
    #pragma unroll
    for (int r = 0; r < 4; ++r) {
      ci[r] = c[(size_t)(b * S + i0 + w16 + quad * 4 + r) * 16 + h];
      m_[r] = -INFINITY;
      l_[r] = 0.f;
    }
    #pragma unroll
    for (int dt = 0; dt < 4; ++dt) o_[dt] = (f32x4){0.f, 0.f, 0.f, 0.f};

    const int ntiles = qt + 1;
    for (int jt = 0; jt < ntiles; ++jt) {
      const int j0 = jt * 64;
      __syncthreads();
      {  // stage K (row-major) and V^T
        const int r = tid >> 2, cc = (tid & 3) * 16;
        const u16* ks = qkvb + (size_t)(b * S + j0 + r) * 3072 + 1024 + h * 64 + cc;
        *(u32x4*)&Ks[r * FS + cc] = *(const u32x4*)ks;
        *(u32x4*)&Ks[r * FS + cc + 8] = *(const u32x4*)(ks + 8);
        const u16* vs = vtg + (size_t)(bh * 64 + r) * 2048 + j0 + cc;
        *(u32x4*)&Vt[r * FS + cc] = *(const u32x4*)vs;
        *(u32x4*)&Vt[r * FS + cc + 8] = *(const u32x4*)(vs + 8);
        if (tid < 64) cjs[tid] = c[(size_t)(b * S + j0 + tid) * 16 + h];
      }
      __syncthreads();

      // scores: S[i][j] for wave's 16 rows x 64 keys
      bf16x8 aq0 = *(const bf16x8*)&Qs[(w16 + lr) * FS + quad * 8];
      bf16x8 aq1 = *(const bf16x8*)&Qs[(w16 + lr) * FS + 32 + quad * 8];
      f32x4 sc[4];
      #pragma unroll
      for (int nt = 0; nt < 4; ++nt) {
        bf16x8 bk0 = *(const bf16x8*)&Ks[(nt * 16 + lr) * FS + quad * 8];
        bf16x8 bk1 = *(const bf16x8*)&Ks[(nt * 16 + lr) * FS + 32 + quad * 8];
        f32x4 z = {0.f, 0.f, 0.f, 0.f};
        z = __builtin_amdgcn_mfma_f32_16x16x32_bf16(aq0, bk0, z, 0, 0, 0);
        z = __builtin_amdgcn_mfma_f32_16x16x32_bf16(aq1, bk1, z, 0, 0, 0);
        sc[nt] = z;
      }
      const bool diag = (jt == qt);
      #pragma unroll
      for (int r = 0; r < 4; ++r) {
        const int i = i0 + w16 + quad * 4 + r;
        float lg[4], mrow = -INFINITY;
        #pragma unroll
        for (int nt = 0; nt < 4; ++nt) {
          const int j = j0 + nt * 16 + lr;
          float v = sc[nt][r] * 0.125f + ci[r] - cjs[nt * 16 + lr];
          if (diag && (j > i)) v = -INFINITY;
          lg[nt] = v;
          mrow = fmaxf(mrow, v);
        }
        #pragma unroll
        for (int off = 1; off < 16; off <<= 1)
          mrow = fmaxf(mrow, __shfl_xor(mrow, off, 64));
        const float mn = fmaxf(m_[r], mrow);
        alpha[r] = __expf(m_[r] - mn);
        m_[r] = mn;
        float rs = 0.f;
        #pragma unroll
        for (int nt = 0; nt < 4; ++nt) {
          const float p = __expf(lg[nt] - mn);
          Ps[(w16 + quad * 4 + r) * FS + nt * 16 + lr] = f2bf(p);
          rs += p;
        }
        #pragma unroll
        for (int off = 1; off < 16; off <<= 1) rs += __shfl_xor(rs, off, 64);
        l_[r] = l_[r] * alpha[r] + rs;
      }
      // make this wave's P writes visible to its own b128 reads
      asm volatile("s_waitcnt lgkmcnt(0)" ::: "memory");
      #pragma unroll
      for (int dt = 0; dt < 4; ++dt)
        #pragma unroll
        for (int r = 0; r < 4; ++r) o_[dt][r] *= alpha[r];
      bf16x8 ap0 = *(const bf16x8*)&Ps[(w16 + lr) * FS + quad * 8];
      bf16x8 ap1 = *(const bf16x8*)&Ps[(w16 + lr) * FS + 32 + quad * 8];
      #pragma unroll
      for (int dt = 0; dt < 4; ++dt) {
        bf16x8 bv0 = *(const bf16x8*)&Vt[(dt * 16 + lr) * FS + quad * 8];
        bf16x8 bv1 = *(const bf16x8*)&Vt[(dt * 16 + lr) * FS + 32 + quad * 8];
        o_[dt] = __builtin_amdgcn_mfma_f32_16x16x32_bf16(ap0, bv0, o_[dt], 0, 0, 0);
        o_[dt] = __builtin_amdgcn_mfma_f32_16x16x32_bf16(ap1, bv1, o_[dt], 0, 0, 0);
      }
    }
    #pragma unroll
    for (int r = 0; r < 4; ++r) {
      const float inv = 1.0f / l_[r];
      const size_t base = (size_t)(b * S + i0 + w16 + quad * 4 + r) * 1024 + h * 64;
      #pragma unroll
      for (int dt = 0; dt < 4; ++dt)
        ctx[base + dt * 16 + lr] = f2bf(o_[dt][r] * inv);
    }
  }
}

// ---------------------------------------------------------------------------
extern "C" void kernel_launch(void* const* d_in, const int* in_sizes, int n_in,
                              void* d_out, int out_size, void* d_ws, size_t ws_size,
                              hipStream_t stream) {
  const float* x    = (const float*)d_in[0];
  const float* ln1g = (const float*)d_in[1];
  const float* ln1b = (const float*)d_in[2];
  const float* wq   = (const float*)d_in[3];
  const float* bq   = (const float*)d_in[4];
  const float* wk   = (const float*)d_in[5];
  const float* bk   = (const float*)d_in[6];
  const float* wv   = (const float*)d_in[7];
  const float* bv   = (const float*)d_in[8];
  const float* wo   = (const float*)d_in[9];
  const float* bo   = (const float*)d_in[10];
  const float* wf   = (const float*)d_in[11];
  const float* bfv  = (const float*)d_in[12];
  const float* ln2g = (const float*)d_in[13];
  const float* ln2b = (const float*)d_in[14];
  const float* w1   = (const float*)d_in[15];
  const float* b1   = (const float*)d_in[16];
  const float* w2   = (const float*)d_in[17];
  const float* b2   = (const float*)d_in[18];
  float* out = (float*)d_out;

  char* ws = (char*)d_ws;
  const size_t MB = 1024 * 1024;
  u16*   wqkvT = (u16*)(ws + 0 * MB);        // 3072x1024 bf16 (6 MB)
  u16*   woT   = (u16*)(ws + 6 * MB);        // 1024x1024 bf16
  u16*   w1T   = (u16*)(ws + 8 * MB);        // 4096x1024 bf16
  u16*   w2T   = (u16*)(ws + 16 * MB);       // 1024x4096 bf16
  u16*   wfT   = (u16*)(ws + 24 * MB);       // 16x1024 bf16
  float* bqkv  = (float*)(ws + 24 * MB + 65536);  // 3072 fp32
  u32*   fctr  = (u32*)(ws + 24 * MB + 131072);   // work-steal counter
  u16*   hbuf  = (u16*)(ws + 25 * MB);       // 4096x1024 bf16
  u16*   ctx   = (u16*)(ws + 33 * MB);       // 4096x1024 bf16
  u16*   qkvb  = (u16*)(ws + 41 * MB);       // 4096x3072 bf16 (24 MB)
  u16*   vtg   = (u16*)(ws + 65 * MB);       // (32*64)x2048 bf16 (8 MB)
  float* cb    = (float*)(ws + 73 * MB);     // 4096x16 fp32
  u16*   act1  = (u16*)(ws + 74 * MB);       // 4096x4096 bf16 (32 MB)

  dim3 blk(256);
  // weight prep (pack3 also zeroes the fattn work-steal counter, on-stream)
  transpose_cast<<<dim3(32, 32), blk, 0, stream>>>(wq, wqkvT, 1024, 1024);
  transpose_cast<<<dim3(32, 32), blk, 0, stream>>>(wk, wqkvT + 1024 * 1024, 1024, 1024);
  transpose_cast<<<dim3(32, 32), blk, 0, stream>>>(wv, wqkvT + 2 * 1024 * 1024, 1024, 1024);
  transpose_cast<<<dim3(32, 32), blk, 0, stream>>>(wo, woT, 1024, 1024);
  transpose_cast<<<dim3(128, 32), blk, 0, stream>>>(w1, w1T, 1024, 4096);
  transpose_cast<<<dim3(32, 128), blk, 0, stream>>>(w2, w2T, 4096, 1024);
  transpose_cast<<<dim3(1, 32), blk, 0, stream>>>(wf, wfT, 1024, 16);
  pack3<<<12, blk, 0, stream>>>(bq, bk, bv, bqkv, fctr);
  // LN1
  ln_kernel<<<4096, blk, 0, stream>>>(x, ln1g, ln1b, hbuf);
  // fused QKV projection -> bf16 (4096 x 3072)
  gemm_bt<<<dim3(24, 32), blk, 0, stream>>>(hbuf, wqkvT, bqkv, nullptr, qkvb,
                                            4096, 3072, 1024, 3);
  // forget gate
  logf_kernel<<<4096, dim3(64), 0, stream>>>(hbuf, wfT, bfv, cb);
  cumsum_kernel<<<32, dim3(64), 0, stream>>>(cb, 2048);
  // V^T prep + attention (work-stealing; counter zeroed by pack3)
  vtrans<<<dim3(64, 2, 32), blk, 0, stream>>>(qkvb, vtg);
  fattn<<<dim3(512), blk, 0, stream>>>(qkvb, vtg, cb, ctx, fctr);
  // out projection + residual -> d_out
  gemm_bt<<<dim3(8, 32), blk, 0, stream>>>(ctx, woT, bo, x, out, 4096, 1024, 1024, 1);
  // LN2
  ln_kernel<<<4096, blk, 0, stream>>>(out, ln2g, ln2b, hbuf);
  // MLP
  gemm_bt<<<dim3(32, 32), blk, 0, stream>>>(hbuf, w1T, b1, nullptr, act1,
                                            4096, 4096, 1024, 2);
  gemm_bt<<<dim3(8, 32), blk, 0, stream>>>(act1, w2T, b2, out, out,
                                           4096, 1024, 4096, 1);
}

// Round 8
// 533.584 us; speedup vs baseline: 5.4072x; 1.0653x over previous
//
#include <hip/hip_runtime.h>
#include <hip/hip_bf16.h>
#include <math.h>

typedef unsigned short u16;
typedef unsigned int u32;
typedef __bf16 bf16x8 __attribute__((ext_vector_type(8)));
typedef float f32x4 __attribute__((ext_vector_type(4)));
typedef u32 u32x4 __attribute__((ext_vector_type(4)));

__device__ __forceinline__ u16 f2bf(float f) {
  __hip_bfloat16 h = __float2bfloat16(f);
  return *reinterpret_cast<u16*>(&h);
}
__device__ __forceinline__ float bf2f(u16 u) {
  return __uint_as_float(((u32)u) << 16);
}

// async global->LDS, 16B per lane; LDS dest = wave-uniform base + lane*16
#define GLL(gp, lp)                                                     \
  __builtin_amdgcn_global_load_lds(                                     \
      (const __attribute__((address_space(1))) void*)(gp),              \
      (__attribute__((address_space(3))) void*)(lp), 16, 0, 0)

// ---------------------------------------------------------------------------
// Transpose + cast fp32 (R x C) -> bf16 (C x R)
// ---------------------------------------------------------------------------
__global__ __launch_bounds__(256) void transpose_cast(
    const float* __restrict__ in, u16* __restrict__ out, int R, int C) {
  __shared__ float tile[32][33];
  int c0 = blockIdx.x * 32, r0 = blockIdx.y * 32;
  int tx = threadIdx.x & 31, ty = threadIdx.x >> 5;
  for (int i = ty; i < 32; i += 8) {
    int r = r0 + i, c = c0 + tx;
    if (r < R && c < C) tile[i][tx] = in[(size_t)r * C + c];
  }
  __syncthreads();
  for (int i = ty; i < 32; i += 8) {
    int c = c0 + i, r = r0 + tx;
    if (c < C && r < R) out[(size_t)c * R + r] = f2bf(tile[tx][i]);
  }
}

// pack bq,bk,bv -> 3072-float bias; ALSO zeroes the fattn work-steal counter
// (on-stream, before fattn; avoids hipMemsetAsync which broke graph capture)
__global__ __launch_bounds__(256) void pack3(
    const float* __restrict__ a, const float* __restrict__ b,
    const float* __restrict__ c, float* __restrict__ o, u32* __restrict__ ctr) {
  int t = blockIdx.x * 256 + threadIdx.x;
  if (t == 0) *ctr = 0u;
  if (t < 1024) o[t] = a[t];
  else if (t < 2048) o[t] = b[t - 1024];
  else if (t < 3072) o[t] = c[t - 2048];
}

// ---------------------------------------------------------------------------
// LayerNorm over last dim (1024), fp32 in -> bf16 out. One block per row.
// ---------------------------------------------------------------------------
__global__ __launch_bounds__(256) void ln_kernel(
    const float* __restrict__ x, const float* __restrict__ g,
    const float* __restrict__ bb, u16* __restrict__ out) {
  __shared__ float red[8];
  const int row = blockIdx.x;
  const float* xr = x + (size_t)row * 1024;
  f32x4 v = *(const f32x4*)(xr + threadIdx.x * 4);
  float s = v[0] + v[1] + v[2] + v[3];
  #pragma unroll
  for (int off = 32; off > 0; off >>= 1) s += __shfl_xor(s, off, 64);
  if ((threadIdx.x & 63) == 0) red[threadIdx.x >> 6] = s;
  __syncthreads();
  float mu = (red[0] + red[1] + red[2] + red[3]) * (1.0f / 1024.0f);
  f32x4 d;
  d[0] = v[0] - mu; d[1] = v[1] - mu; d[2] = v[2] - mu; d[3] = v[3] - mu;
  float sq = d[0]*d[0] + d[1]*d[1] + d[2]*d[2] + d[3]*d[3];
  #pragma unroll
  for (int off = 32; off > 0; off >>= 1) sq += __shfl_xor(sq, off, 64);
  if ((threadIdx.x & 63) == 0) red[4 + (threadIdx.x >> 6)] = sq;
  __syncthreads();
  float var = (red[4] + red[5] + red[6] + red[7]) * (1.0f / 1024.0f);
  float rstd = rsqrtf(var + 1e-5f);
  int cb = threadIdx.x * 4;
  #pragma unroll
  for (int e = 0; e < 4; ++e)
    out[(size_t)row * 1024 + cb + e] = f2bf(d[e] * rstd * g[cb + e] + bb[cb + e]);
}

// ---------------------------------------------------------------------------
// bf16 MFMA GEMM with global_load_lds width-16 staging (m97 structure).
// C[M,N] = A[M,K] * Bt[N,K]^T + bias. 128x128 tile, BK=32, 4 waves 2x2,
// each wave 4x4 of 16x16x32.
// mode 0: fp32 out          mode 1: fp32 out + res
// mode 2: bf16 out = gelu   mode 3: bf16 out
// NOTE: every constant-trip loop is #pragma unroll'd (round-2 post-mortem:
// without it acc spilled to scratch -> 3.4 GB HBM/dispatch, 52 TF).
// ---------------------------------------------------------------------------
__global__ __launch_bounds__(256) void gemm_bt(
    const u16* __restrict__ A, const u16* __restrict__ Bt,
    const float* __restrict__ bias, const float* __restrict__ res,
    void* __restrict__ outp, int M, int N, int K, int mode) {
  __shared__ u16 As[128 * 32];
  __shared__ u16 Bs[128 * 32];
  const int tid = threadIdx.x;
  const int m0 = blockIdx.y * 128, n0 = blockIdx.x * 128;
  const int wave = tid >> 6, lane = tid & 63;
  const int wm = (wave >> 1) * 64, wn = (wave & 1) * 64;
  const int lr = lane & 15, quad = lane >> 4;
  const int g0 = wave * 2;
  const int srow0 = g0 * 16 + (lane >> 2);
  const int scol = (lane & 3) * 8;
  const u16* Ag0 = A + (size_t)(m0 + srow0) * K + scol;
  const u16* Ag1 = A + (size_t)(m0 + srow0 + 16) * K + scol;
  const u16* Bg0 = Bt + (size_t)(n0 + srow0) * K + scol;
  const u16* Bg1 = Bt + (size_t)(n0 + srow0 + 16) * K + scol;
  u16* Al0 = As + g0 * 512;
  u16* Al1 = As + (g0 + 1) * 512;
  u16* Bl0 = Bs + g0 * 512;
  u16* Bl1 = Bs + (g0 + 1) * 512;

  f32x4 acc[4][4] = {};

  for (int k0 = 0; k0 < K; k0 += 32) {
    GLL(Ag0 + k0, Al0);
    GLL(Ag1 + k0, Al1);
    GLL(Bg0 + k0, Bl0);
    GLL(Bg1 + k0, Bl1);
    __syncthreads();
    bf16x8 af[4], bfr[4];
    #pragma unroll
    for (int t = 0; t < 4; ++t) {
      af[t]  = *(const bf16x8*)&As[(wm + t * 16 + lr) * 32 + quad * 8];
      bfr[t] = *(const bf16x8*)&Bs[(wn + t * 16 + lr) * 32 + quad * 8];
    }
    #pragma unroll
    for (int mt = 0; mt < 4; ++mt)
      #pragma unroll
      for (int nt = 0; nt < 4; ++nt)
        acc[mt][nt] = __builtin_amdgcn_mfma_f32_16x16x32_bf16(
            af[mt], bfr[nt], acc[mt][nt], 0, 0, 0);
    __syncthreads();
  }

  #pragma unroll
  for (int mt = 0; mt < 4; ++mt) {
    #pragma unroll
    for (int nt = 0; nt < 4; ++nt) {
      const int col = n0 + wn + nt * 16 + lr;
      const float bvv = bias[col];
      #pragma unroll
      for (int rr = 0; rr < 4; ++rr) {
        const int row = m0 + wm + mt * 16 + quad * 4 + rr;
        const size_t idx = (size_t)row * N + col;
        float v = acc[mt][nt][rr] + bvv;
        if (mode == 0) {
          ((float*)outp)[idx] = v;
        } else if (mode == 1) {
          ((float*)outp)[idx] = v + res[idx];
        } else if (mode == 2) {
          float gl = 0.5f * v * (1.0f + erff(v * 0.70710678118654752f));
          ((u16*)outp)[idx] = f2bf(gl);
        } else {
          ((u16*)outp)[idx] = f2bf(v);
        }
      }
    }
  }
}

// ---------------------------------------------------------------------------
// bf16 MFMA GEMM, 128x64 tile (N-skinny), self-contained. Grid (N/64, M/128)
// -> 512 blocks = 2/CU at N=1024 (round-5: 1 block/CU ran 75 TF, latency-
// bound with no co-resident overlap). 4 waves 2x2: wave tile 64x32, acc[4][2].
// Same staging discipline as gemm_bt (wave-uniform GLL base + lane*16).
// ---------------------------------------------------------------------------
__global__ __launch_bounds__(256) void gemm_n64(
    const u16* __restrict__ A, const u16* __restrict__ Bt,
    const float* __restrict__ bias, const float* __restrict__ res,
    void* __restrict__ outp, int M, int N, int K, int mode) {
  __shared__ u16 As[128 * 32];
  __shared__ u16 Bs[64 * 32];
  const int tid = threadIdx.x;
  const int m0 = blockIdx.y * 128, n0 = blockIdx.x * 64;
  const int wave = tid >> 6, lane = tid & 63;
  const int wm = (wave >> 1) * 64, wn = (wave & 1) * 32;
  const int lr = lane & 15, quad = lane >> 4;
  const int g0 = wave * 2;
  const int srow = lane >> 2;
  const int scol = (lane & 3) * 8;
  const u16* Ag0 = A + (size_t)(m0 + g0 * 16 + srow) * K + scol;
  const u16* Ag1 = A + (size_t)(m0 + g0 * 16 + 16 + srow) * K + scol;
  const u16* Bg  = Bt + (size_t)(n0 + wave * 16 + srow) * K + scol;
  u16* Al0 = As + g0 * 512;
  u16* Al1 = As + (g0 + 1) * 512;
  u16* Bl  = Bs + wave * 512;

  f32x4 acc[4][2] = {};

  for (int k0 = 0; k0 < K; k0 += 32) {
    GLL(Ag0 + k0, Al0);
    GLL(Ag1 + k0, Al1);
    GLL(Bg + k0, Bl);
    __syncthreads();
    bf16x8 af[4], bfr[2];
    #pragma unroll
    for (int t = 0; t < 4; ++t)
      af[t] = *(const bf16x8*)&As[(wm + t * 16 + lr) * 32 + quad * 8];
    #pragma unroll
    for (int t = 0; t < 2; ++t)
      bfr[t] = *(const bf16x8*)&Bs[(wn + t * 16 + lr) * 32 + quad * 8];
    #pragma unroll
    for (int mt = 0; mt < 4; ++mt)
      #pragma unroll
      for (int nt = 0; nt < 2; ++nt)
        acc[mt][nt] = __builtin_amdgcn_mfma_f32_16x16x32_bf16(
            af[mt], bfr[nt], acc[mt][nt], 0, 0, 0);
    __syncthreads();
  }

  #pragma unroll
  for (int mt = 0; mt < 4; ++mt) {
    #pragma unroll
    for (int nt = 0; nt < 2; ++nt) {
      const int col = n0 + wn + nt * 16 + lr;
      const float bvv = bias[col];
      #pragma unroll
      for (int rr = 0; rr < 4; ++rr) {
        const int row = m0 + wm + mt * 16 + quad * 4 + rr;
        const size_t idx = (size_t)row * N + col;
        float v = acc[mt][nt][rr] + bvv;
        if (mode == 0) {
          ((float*)outp)[idx] = v;
        } else if (mode == 1) {
          ((float*)outp)[idx] = v + res[idx];
        } else if (mode == 2) {
          float gl = 0.5f * v * (1.0f + erff(v * 0.70710678118654752f));
          ((u16*)outp)[idx] = f2bf(gl);
        } else {
          ((u16*)outp)[idx] = f2bf(v);
        }
      }
    }
  }
}

// ---------------------------------------------------------------------------
// logf = log_sigmoid(h @ wf + bf), one wave per row. wfT is (16 x 1024) bf16.
// ---------------------------------------------------------------------------
__global__ __launch_bounds__(64) void logf_kernel(
    const u16* __restrict__ h, const u16* __restrict__ wfT,
    const float* __restrict__ bfv, float* __restrict__ c) {
  const int row = blockIdx.x;
  const int lane = threadIdx.x;
  float acc[16];
  #pragma unroll
  for (int n = 0; n < 16; ++n) acc[n] = 0.f;
  for (int t = 0; t < 16; ++t) {
    int kidx = t * 64 + lane;
    float hv = bf2f(h[(size_t)row * 1024 + kidx]);
    #pragma unroll
    for (int n = 0; n < 16; ++n)
      acc[n] += hv * bf2f(wfT[n * 1024 + kidx]);
  }
  float z = 0.f;
  #pragma unroll
  for (int n = 0; n < 16; ++n) {
    float r = acc[n];
    #pragma unroll
    for (int off = 1; off < 64; off <<= 1) r += __shfl_xor(r, off, 64);
    if (lane == n) z = r;
  }
  if (lane < 16) {
    z += bfv[lane];
    float lf = (z >= 0.f) ? -log1pf(expf(-z)) : (z - log1pf(expf(z)));
    c[(size_t)row * 16 + lane] = lf;
  }
}

__global__ __launch_bounds__(64) void cumsum_kernel(float* __restrict__ c, int S) {
  const int b = blockIdx.x >> 4, h = blockIdx.x & 15;
  const int lane = threadIdx.x;
  float carry = 0.f;
  for (int s0 = 0; s0 < S; s0 += 64) {
    float v = c[(size_t)(b * S + s0 + lane) * 16 + h];
    #pragma unroll
    for (int off = 1; off < 64; off <<= 1) {
      float t = __shfl_up(v, off, 64);
      if (lane >= off) v += t;
    }
    v += carry;
    c[(size_t)(b * S + s0 + lane) * 16 + h] = v;
    carry = __shfl(v, 63, 64);
  }
}

// ---------------------------------------------------------------------------
// V^T prep: qkvb V-part (token-major) -> vtg[(b,h,d), s] bf16
// ---------------------------------------------------------------------------
__global__ __launch_bounds__(256) void vtrans(
    const u16* __restrict__ qkvb, u16* __restrict__ vtg) {
  __shared__ u16 t[32][33];
  const int bh = blockIdx.z, b = bh >> 4, h = bh & 15;
  const int s0 = blockIdx.x * 32, d0 = blockIdx.y * 32;
  const int tx = threadIdx.x & 31, ty = threadIdx.x >> 5;
  for (int i = ty; i < 32; i += 8)
    t[i][tx] = qkvb[(size_t)(b * 2048 + s0 + i) * 3072 + 2048 + h * 64 + d0 + tx];
  __syncthreads();
  for (int i = ty; i < 32; i += 8)
    vtg[(size_t)(bh * 64 + d0 + i) * 2048 + s0 + tx] = t[tx][i];
}

// ---------------------------------------------------------------------------
// MFMA flash attention with forget-gate decay bias. WORK-STEALING:
// 512 blocks pull (t, bh) items (descending work) from a global counter ->
// LPT balance regardless of block->CU mapping (round-3: static grid had 4x
// co-resident imbalance). 4 waves; wave w owns q-rows [w*16, w*16+16).
// ---------------------------------------------------------------------------
#define FS 72
#define NITEMS 1024  // 32 q-tiles * 32 bh

__global__ __launch_bounds__(256) void fattn(
    const u16* __restrict__ qkvb, const u16* __restrict__ vtg,
    const float* __restrict__ c, u16* __restrict__ ctx, u32* __restrict__ ctr) {
  __shared__ u16 Qs[64 * FS];
  __shared__ u16 Ks[64 * FS];
  __shared__ u16 Vt[64 * FS];
  __shared__ u16 Ps[64 * FS];
  __shared__ float cjs[64];
  __shared__ u32 sh_item;
  const int S = 2048;
  const int tid = threadIdx.x, wave = tid >> 6, lane = tid & 63;
  const int lr = lane & 15, quad = lane >> 4;
  const int w16 = wave * 16;

  for (;;) {
    if (tid == 0) sh_item = atomicAdd(ctr, 1u);
    __syncthreads();
    const u32 item = sh_item;
    if (item >= NITEMS) return;
    const int qt = 31 - (int)(item >> 5);       // descending work
    const int bh = (int)(item & 31), b = bh >> 4, h = bh & 15;
    const int i0 = qt * 64;

    {  // stage Q tile (64x64 bf16)
      const int r = tid >> 2, cc = (tid & 3) * 16;
      const u16* src = qkvb + (size_t)(b * S + i0 + r) * 3072 + h * 64 + cc;
      *(u32x4*)&Qs[r * FS + cc] = *(const u32x4*)src;
      *(u32x4*)&Qs[r * FS + cc + 8] = *(const u32x4*)(src + 8);
    }
    float ci[4], m_[4], l_[4], alpha[4];
    f32x4 o_[4];
    #pragma unroll
    for (int r = 0; r < 4; ++r) {
      ci[r] = c[(size_t)(b * S + i0 + w16 + quad * 4 + r) * 16 + h];
      m_[r] = -INFINITY;
      l_[r] = 0.f;
    }
    #pragma unroll
    for (int dt = 0; dt < 4; ++dt) o_[dt] = (f32x4){0.f, 0.f, 0.f, 0.f};

    const int ntiles = qt + 1;
    for (int jt = 0; jt < ntiles; ++jt) {
      const int j0 = jt * 64;
      __syncthreads();
      {  // stage K (row-major) and V^T
        const int r = tid >> 2, cc = (tid & 3) * 16;
        const u16* ks = qkvb + (size_t)(b * S + j0 + r) * 3072 + 1024 + h * 64 + cc;
        *(u32x4*)&Ks[r * FS + cc] = *(const u32x4*)ks;
        *(u32x4*)&Ks[r * FS + cc + 8] = *(const u32x4*)(ks + 8);
        const u16* vs = vtg + (size_t)(bh * 64 + r) * 2048 + j0 + cc;
        *(u32x4*)&Vt[r * FS + cc] = *(const u32x4*)vs;
        *(u32x4*)&Vt[r * FS + cc + 8] = *(const u32x4*)(vs + 8);
        if (tid < 64) cjs[tid] = c[(size_t)(b * S + j0 + tid) * 16 + h];
      }
      __syncthreads();

      bf16x8 aq0 = *(const bf16x8*)&Qs[(w16 + lr) * FS + quad * 8];
      bf16x8 aq1 = *(const bf16x8*)&Qs[(w16 + lr) * FS + 32 + quad * 8];
      f32x4 sc[4];
      #pragma unroll
      for (int nt = 0; nt < 4; ++nt) {
        bf16x8 bk0 = *(const bf16x8*)&Ks[(nt * 16 + lr) * FS + quad * 8];
        bf16x8 bk1 = *(const bf16x8*)&Ks[(nt * 16 + lr) * FS + 32 + quad * 8];
        f32x4 z = {0.f, 0.f, 0.f, 0.f};
        z = __builtin_amdgcn_mfma_f32_16x16x32_bf16(aq0, bk0, z, 0, 0, 0);
        z = __builtin_amdgcn_mfma_f32_16x16x32_bf16(aq1, bk1, z, 0, 0, 0);
        sc[nt] = z;
      }
      const bool diag = (jt == qt);
      #pragma unroll
      for (int r = 0; r < 4; ++r) {
        const int i = i0 + w16 + quad * 4 + r;
        float lg[4], mrow = -INFINITY;
        #pragma unroll
        for (int nt = 0; nt < 4; ++nt) {
          const int j = j0 + nt * 16 + lr;
          float v = sc[nt][r] * 0.125f + ci[r] - cjs[nt * 16 + lr];
          if (diag && (j > i)) v = -INFINITY;
          lg[nt] = v;
          mrow = fmaxf(mrow, v);
        }
        #pragma unroll
        for (int off = 1; off < 16; off <<= 1)
          mrow = fmaxf(mrow, __shfl_xor(mrow, off, 64));
        const float mn = fmaxf(m_[r], mrow);
        alpha[r] = __expf(m_[r] - mn);
        m_[r] = mn;
        float rs = 0.f;
        #pragma unroll
        for (int nt = 0; nt < 4; ++nt) {
          const float p = __expf(lg[nt] - mn);
          Ps[(w16 + quad * 4 + r) * FS + nt * 16 + lr] = f2bf(p);
          rs += p;
        }
        #pragma unroll
        for (int off = 1; off < 16; off <<= 1) rs += __shfl_xor(rs, off, 64);
        l_[r] = l_[r] * alpha[r] + rs;
      }
      asm volatile("s_waitcnt lgkmcnt(0)" ::: "memory");
      #pragma unroll
      for (int dt = 0; dt < 4; ++dt)
        #pragma unroll
        for (int r = 0; r < 4; ++r) o_[dt][r] *= alpha[r];
      bf16x8 ap0 = *(const bf16x8*)&Ps[(w16 + lr) * FS + quad * 8];
      bf16x8 ap1 = *(const bf16x8*)&Ps[(w16 + lr) * FS + 32 + quad * 8];
      #pragma unroll
      for (int dt = 0; dt < 4; ++dt) {
        bf16x8 bv0 = *(const bf16x8*)&Vt[(dt * 16 + lr) * FS + quad * 8];
        bf16x8 bv1 = *(const bf16x8*)&Vt[(dt * 16 + lr) * FS + 32 + quad * 8];
        o_[dt] = __builtin_amdgcn_mfma_f32_16x16x32_bf16(ap0, bv0, o_[dt], 0, 0, 0);
        o_[dt] = __builtin_amdgcn_mfma_f32_16x16x32_bf16(ap1, bv1, o_[dt], 0, 0, 0);
      }
    }
    #pragma unroll
    for (int r = 0; r < 4; ++r) {
      const float inv = 1.0f / l_[r];
      const size_t base = (size_t)(b * S + i0 + w16 + quad * 4 + r) * 1024 + h * 64;
      #pragma unroll
      for (int dt = 0; dt < 4; ++dt)
        ctx[base + dt * 16 + lr] = f2bf(o_[dt][r] * inv);
    }
  }
}

// ---------------------------------------------------------------------------
extern "C" void kernel_launch(void* const* d_in, const int* in_sizes, int n_in,
                              void* d_out, int out_size, void* d_ws, size_t ws_size,
                              hipStream_t stream) {
  const float* x    = (const float*)d_in[0];
  const float* ln1g = (const float*)d_in[1];
  const float* ln1b = (const float*)d_in[2];
  const float* wq   = (const float*)d_in[3];
  const float* bq   = (const float*)d_in[4];
  const float* wk   = (const float*)d_in[5];
  const float* bk   = (const float*)d_in[6];
  const float* wv   = (const float*)d_in[7];
  const float* bv   = (const float*)d_in[8];
  const float* wo   = (const float*)d_in[9];
  const float* bo   = (const float*)d_in[10];
  const float* wf   = (const float*)d_in[11];
  const float* bfv  = (const float*)d_in[12];
  const float* ln2g = (const float*)d_in[13];
  const float* ln2b = (const float*)d_in[14];
  const float* w1   = (const float*)d_in[15];
  const float* b1   = (const float*)d_in[16];
  const float* w2   = (const float*)d_in[17];
  const float* b2   = (const float*)d_in[18];
  float* out = (float*)d_out;

  char* ws = (char*)d_ws;
  const size_t MB = 1024 * 1024;
  u16*   wqkvT = (u16*)(ws + 0 * MB);        // 3072x1024 bf16 (6 MB)
  u16*   woT   = (u16*)(ws + 6 * MB);        // 1024x1024 bf16
  u16*   w1T   = (u16*)(ws + 8 * MB);        // 4096x1024 bf16
  u16*   w2T   = (u16*)(ws + 16 * MB);       // 1024x4096 bf16
  u16*   wfT   = (u16*)(ws + 24 * MB);       // 16x1024 bf16
  float* bqkv  = (float*)(ws + 24 * MB + 65536);  // 3072 fp32
  u32*   fctr  = (u32*)(ws + 24 * MB + 131072);   // work-steal counter
  u16*   hbuf  = (u16*)(ws + 25 * MB);       // 4096x1024 bf16
  u16*   ctx   = (u16*)(ws + 33 * MB);       // 4096x1024 bf16
  u16*   qkvb  = (u16*)(ws + 41 * MB);       // 4096x3072 bf16 (24 MB)
  u16*   vtg   = (u16*)(ws + 65 * MB);       // (32*64)x2048 bf16 (8 MB)
  float* cb    = (float*)(ws + 73 * MB);     // 4096x16 fp32
  u16*   act1  = (u16*)(ws + 74 * MB);       // 4096x4096 bf16 (32 MB)

  dim3 blk(256);
  // weight prep (pack3 also zeroes the fattn work-steal counter, on-stream)
  transpose_cast<<<dim3(32, 32), blk, 0, stream>>>(wq, wqkvT, 1024, 1024);
  transpose_cast<<<dim3(32, 32), blk, 0, stream>>>(wk, wqkvT + 1024 * 1024, 1024, 1024);
  transpose_cast<<<dim3(32, 32), blk, 0, stream>>>(wv, wqkvT + 2 * 1024 * 1024, 1024, 1024);
  transpose_cast<<<dim3(32, 32), blk, 0, stream>>>(wo, woT, 1024, 1024);
  transpose_cast<<<dim3(128, 32), blk, 0, stream>>>(w1, w1T, 1024, 4096);
  transpose_cast<<<dim3(32, 128), blk, 0, stream>>>(w2, w2T, 4096, 1024);
  transpose_cast<<<dim3(1, 32), blk, 0, stream>>>(wf, wfT, 1024, 16);
  pack3<<<12, blk, 0, stream>>>(bq, bk, bv, bqkv, fctr);
  // LN1
  ln_kernel<<<4096, blk, 0, stream>>>(x, ln1g, ln1b, hbuf);
  // fused QKV projection -> bf16 (4096 x 3072), 768 blocks = 3/CU
  gemm_bt<<<dim3(24, 32), blk, 0, stream>>>(hbuf, wqkvT, bqkv, nullptr, qkvb,
                                            4096, 3072, 1024, 3);
  // forget gate
  logf_kernel<<<4096, dim3(64), 0, stream>>>(hbuf, wfT, bfv, cb);
  cumsum_kernel<<<32, dim3(64), 0, stream>>>(cb, 2048);
  // V^T prep + attention (work-stealing; counter zeroed by pack3)
  vtrans<<<dim3(64, 2, 32), blk, 0, stream>>>(qkvb, vtg);
  fattn<<<dim3(512), blk, 0, stream>>>(qkvb, vtg, cb, ctx, fctr);
  // out projection + residual -> d_out (N=1024: n64 tiles, 512 blocks = 2/CU)
  gemm_n64<<<dim3(16, 32), blk, 0, stream>>>(ctx, woT, bo, x, out,
                                             4096, 1024, 1024, 1);
  // LN2
  ln_kernel<<<4096, blk, 0, stream>>>(out, ln2g, ln2b, hbuf);
  // MLP1: 1024 blocks = 4/CU
  gemm_bt<<<dim3(32, 32), blk, 0, stream>>>(hbuf, w1T, b1, nullptr, act1,
                                            4096, 4096, 1024, 2);
  // MLP2 (N=1024: n64 tiles, 512 blocks = 2/CU)
  gemm_n64<<<dim3(16, 32), blk, 0, stream>>>(act1, w2T, b2, out, out,
                                             4096, 1024, 4096, 1);
}

// Round 9
// 528.664 us; speedup vs baseline: 5.4575x; 1.0093x over previous
//
#include <hip/hip_runtime.h>
#include <hip/hip_bf16.h>
#include <math.h>

typedef unsigned short u16;
typedef unsigned int u32;
typedef __bf16 bf16x8 __attribute__((ext_vector_type(8)));
typedef float f32x4 __attribute__((ext_vector_type(4)));
typedef u32 u32x4 __attribute__((ext_vector_type(4)));

__device__ __forceinline__ u16 f2bf(float f) {
  __hip_bfloat16 h = __float2bfloat16(f);
  return *reinterpret_cast<u16*>(&h);
}
__device__ __forceinline__ float bf2f(u16 u) {
  return __uint_as_float(((u32)u) << 16);
}

// async global->LDS, 16B per lane; LDS dest = wave-uniform base + lane*16
#define GLL(gp, lp)                                                     \
  __builtin_amdgcn_global_load_lds(                                     \
      (const __attribute__((address_space(1))) void*)(gp),              \
      (__attribute__((address_space(3))) void*)(lp), 16, 0, 0)

// ---------------------------------------------------------------------------
// Transpose + cast fp32 (R x C) -> bf16 (C x R)
// ---------------------------------------------------------------------------
__global__ __launch_bounds__(256) void transpose_cast(
    const float* __restrict__ in, u16* __restrict__ out, int R, int C) {
  __shared__ float tile[32][33];
  int c0 = blockIdx.x * 32, r0 = blockIdx.y * 32;
  int tx = threadIdx.x & 31, ty = threadIdx.x >> 5;
  for (int i = ty; i < 32; i += 8) {
    int r = r0 + i, c = c0 + tx;
    if (r < R && c < C) tile[i][tx] = in[(size_t)r * C + c];
  }
  __syncthreads();
  for (int i = ty; i < 32; i += 8) {
    int c = c0 + i, r = r0 + tx;
    if (c < C && r < R) out[(size_t)c * R + r] = f2bf(tile[tx][i]);
  }
}

// pack bq,bk,bv -> 3072-float bias; ALSO zeroes the fattn work-steal counter
// (on-stream, before fattn; avoids hipMemsetAsync which broke graph capture)
__global__ __launch_bounds__(256) void pack3(
    const float* __restrict__ a, const float* __restrict__ b,
    const float* __restrict__ c, float* __restrict__ o, u32* __restrict__ ctr) {
  int t = blockIdx.x * 256 + threadIdx.x;
  if (t == 0) *ctr = 0u;
  if (t < 1024) o[t] = a[t];
  else if (t < 2048) o[t] = b[t - 1024];
  else if (t < 3072) o[t] = c[t - 2048];
}

// ---------------------------------------------------------------------------
// LayerNorm over last dim (1024), fp32 in -> bf16 out. One block per row.
// ---------------------------------------------------------------------------
__global__ __launch_bounds__(256) void ln_kernel(
    const float* __restrict__ x, const float* __restrict__ g,
    const float* __restrict__ bb, u16* __restrict__ out) {
  __shared__ float red[8];
  const int row = blockIdx.x;
  const float* xr = x + (size_t)row * 1024;
  f32x4 v = *(const f32x4*)(xr + threadIdx.x * 4);
  float s = v[0] + v[1] + v[2] + v[3];
  #pragma unroll
  for (int off = 32; off > 0; off >>= 1) s += __shfl_xor(s, off, 64);
  if ((threadIdx.x & 63) == 0) red[threadIdx.x >> 6] = s;
  __syncthreads();
  float mu = (red[0] + red[1] + red[2] + red[3]) * (1.0f / 1024.0f);
  f32x4 d;
  d[0] = v[0] - mu; d[1] = v[1] - mu; d[2] = v[2] - mu; d[3] = v[3] - mu;
  float sq = d[0]*d[0] + d[1]*d[1] + d[2]*d[2] + d[3]*d[3];
  #pragma unroll
  for (int off = 32; off > 0; off >>= 1) sq += __shfl_xor(sq, off, 64);
  if ((threadIdx.x & 63) == 0) red[4 + (threadIdx.x >> 6)] = sq;
  __syncthreads();
  float var = (red[4] + red[5] + red[6] + red[7]) * (1.0f / 1024.0f);
  float rstd = rsqrtf(var + 1e-5f);
  int cb = threadIdx.x * 4;
  #pragma unroll
  for (int e = 0; e < 4; ++e)
    out[(size_t)row * 1024 + cb + e] = f2bf(d[e] * rstd * g[cb + e] + bb[cb + e]);
}

// ---------------------------------------------------------------------------
// bf16 MFMA GEMM with global_load_lds width-16 staging (m97 structure).
// C[M,N] = A[M,K] * Bt[N,K]^T + bias. 128x128 tile, BK=32, 4 waves 2x2,
// each wave 4x4 of 16x16x32.
// mode 0: fp32 out          mode 1: fp32 out + res
// mode 2: bf16 out = gelu   mode 3: bf16 out
// NOTE: every constant-trip loop is #pragma unroll'd (round-2 post-mortem:
// without it acc spilled to scratch -> 3.4 GB HBM/dispatch, 52 TF).
// ---------------------------------------------------------------------------
__global__ __launch_bounds__(256) void gemm_bt(
    const u16* __restrict__ A, const u16* __restrict__ Bt,
    const float* __restrict__ bias, const float* __restrict__ res,
    void* __restrict__ outp, int M, int N, int K, int mode) {
  __shared__ u16 As[128 * 32];
  __shared__ u16 Bs[128 * 32];
  const int tid = threadIdx.x;
  const int m0 = blockIdx.y * 128, n0 = blockIdx.x * 128;
  const int wave = tid >> 6, lane = tid & 63;
  const int wm = (wave >> 1) * 64, wn = (wave & 1) * 64;
  const int lr = lane & 15, quad = lane >> 4;
  const int g0 = wave * 2;
  const int srow0 = g0 * 16 + (lane >> 2);
  const int scol = (lane & 3) * 8;
  const u16* Ag0 = A + (size_t)(m0 + srow0) * K + scol;
  const u16* Ag1 = A + (size_t)(m0 + srow0 + 16) * K + scol;
  const u16* Bg0 = Bt + (size_t)(n0 + srow0) * K + scol;
  const u16* Bg1 = Bt + (size_t)(n0 + srow0 + 16) * K + scol;
  u16* Al0 = As + g0 * 512;
  u16* Al1 = As + (g0 + 1) * 512;
  u16* Bl0 = Bs + g0 * 512;
  u16* Bl1 = Bs + (g0 + 1) * 512;

  f32x4 acc[4][4] = {};

  for (int k0 = 0; k0 < K; k0 += 32) {
    GLL(Ag0 + k0, Al0);
    GLL(Ag1 + k0, Al1);
    GLL(Bg0 + k0, Bl0);
    GLL(Bg1 + k0, Bl1);
    __syncthreads();
    bf16x8 af[4], bfr[4];
    #pragma unroll
    for (int t = 0; t < 4; ++t) {
      af[t]  = *(const bf16x8*)&As[(wm + t * 16 + lr) * 32 + quad * 8];
      bfr[t] = *(const bf16x8*)&Bs[(wn + t * 16 + lr) * 32 + quad * 8];
    }
    #pragma unroll
    for (int mt = 0; mt < 4; ++mt)
      #pragma unroll
      for (int nt = 0; nt < 4; ++nt)
        acc[mt][nt] = __builtin_amdgcn_mfma_f32_16x16x32_bf16(
            af[mt], bfr[nt], acc[mt][nt], 0, 0, 0);
    __syncthreads();
  }

  #pragma unroll
  for (int mt = 0; mt < 4; ++mt) {
    #pragma unroll
    for (int nt = 0; nt < 4; ++nt) {
      const int col = n0 + wn + nt * 16 + lr;
      const float bvv = bias[col];
      #pragma unroll
      for (int rr = 0; rr < 4; ++rr) {
        const int row = m0 + wm + mt * 16 + quad * 4 + rr;
        const size_t idx = (size_t)row * N + col;
        float v = acc[mt][nt][rr] + bvv;
        if (mode == 0) {
          ((float*)outp)[idx] = v;
        } else if (mode == 1) {
          ((float*)outp)[idx] = v + res[idx];
        } else if (mode == 2) {
          float gl = 0.5f * v * (1.0f + erff(v * 0.70710678118654752f));
          ((u16*)outp)[idx] = f2bf(gl);
        } else {
          ((u16*)outp)[idx] = f2bf(v);
        }
      }
    }
  }
}

// ---------------------------------------------------------------------------
// bf16 MFMA GEMM, 128x64 tile (N-skinny), self-contained. Grid (N/64, M/128)
// -> 512 blocks = 2/CU at N=1024 (round-5: 1 block/CU ran 75 TF, latency-
// bound with no co-resident overlap). 4 waves 2x2: wave tile 64x32, acc[4][2].
// Same staging discipline as gemm_bt (wave-uniform GLL base + lane*16).
// ---------------------------------------------------------------------------
__global__ __launch_bounds__(256) void gemm_n64(
    const u16* __restrict__ A, const u16* __restrict__ Bt,
    const float* __restrict__ bias, const float* __restrict__ res,
    void* __restrict__ outp, int M, int N, int K, int mode) {
  __shared__ u16 As[128 * 32];
  __shared__ u16 Bs[64 * 32];
  const int tid = threadIdx.x;
  const int m0 = blockIdx.y * 128, n0 = blockIdx.x * 64;
  const int wave = tid >> 6, lane = tid & 63;
  const int wm = (wave >> 1) * 64, wn = (wave & 1) * 32;
  const int lr = lane & 15, quad = lane >> 4;
  const int g0 = wave * 2;
  const int srow = lane >> 2;
  const int scol = (lane & 3) * 8;
  const u16* Ag0 = A + (size_t)(m0 + g0 * 16 + srow) * K + scol;
  const u16* Ag1 = A + (size_t)(m0 + g0 * 16 + 16 + srow) * K + scol;
  const u16* Bg  = Bt + (size_t)(n0 + wave * 16 + srow) * K + scol;
  u16* Al0 = As + g0 * 512;
  u16* Al1 = As + (g0 + 1) * 512;
  u16* Bl  = Bs + wave * 512;

  f32x4 acc[4][2] = {};

  for (int k0 = 0; k0 < K; k0 += 32) {
    GLL(Ag0 + k0, Al0);
    GLL(Ag1 + k0, Al1);
    GLL(Bg + k0, Bl);
    __syncthreads();
    bf16x8 af[4], bfr[2];
    #pragma unroll
    for (int t = 0; t < 4; ++t)
      af[t] = *(const bf16x8*)&As[(wm + t * 16 + lr) * 32 + quad * 8];
    #pragma unroll
    for (int t = 0; t < 2; ++t)
      bfr[t] = *(const bf16x8*)&Bs[(wn + t * 16 + lr) * 32 + quad * 8];
    #pragma unroll
    for (int mt = 0; mt < 4; ++mt)
      #pragma unroll
      for (int nt = 0; nt < 2; ++nt)
        acc[mt][nt] = __builtin_amdgcn_mfma_f32_16x16x32_bf16(
            af[mt], bfr[nt], acc[mt][nt], 0, 0, 0);
    __syncthreads();
  }

  #pragma unroll
  for (int mt = 0; mt < 4; ++mt) {
    #pragma unroll
    for (int nt = 0; nt < 2; ++nt) {
      const int col = n0 + wn + nt * 16 + lr;
      const float bvv = bias[col];
      #pragma unroll
      for (int rr = 0; rr < 4; ++rr) {
        const int row = m0 + wm + mt * 16 + quad * 4 + rr;
        const size_t idx = (size_t)row * N + col;
        float v = acc[mt][nt][rr] + bvv;
        if (mode == 0) {
          ((float*)outp)[idx] = v;
        } else if (mode == 1) {
          ((float*)outp)[idx] = v + res[idx];
        } else if (mode == 2) {
          float gl = 0.5f * v * (1.0f + erff(v * 0.70710678118654752f));
          ((u16*)outp)[idx] = f2bf(gl);
        } else {
          ((u16*)outp)[idx] = f2bf(v);
        }
      }
    }
  }
}

// ---------------------------------------------------------------------------
// logf = log_sigmoid(h @ wf + bf), one wave per row. wfT is (16 x 1024) bf16.
// ---------------------------------------------------------------------------
__global__ __launch_bounds__(64) void logf_kernel(
    const u16* __restrict__ h, const u16* __restrict__ wfT,
    const float* __restrict__ bfv, float* __restrict__ c) {
  const int row = blockIdx.x;
  const int lane = threadIdx.x;
  float acc[16];
  #pragma unroll
  for (int n = 0; n < 16; ++n) acc[n] = 0.f;
  for (int t = 0; t < 16; ++t) {
    int kidx = t * 64 + lane;
    float hv = bf2f(h[(size_t)row * 1024 + kidx]);
    #pragma unroll
    for (int n = 0; n < 16; ++n)
      acc[n] += hv * bf2f(wfT[n * 1024 + kidx]);
  }
  float z = 0.f;
  #pragma unroll
  for (int n = 0; n < 16; ++n) {
    float r = acc[n];
    #pragma unroll
    for (int off = 1; off < 64; off <<= 1) r += __shfl_xor(r, off, 64);
    if (lane == n) z = r;
  }
  if (lane < 16) {
    z += bfv[lane];
    float lf = (z >= 0.f) ? -log1pf(expf(-z)) : (z - log1pf(expf(z)));
    c[(size_t)row * 16 + lane] = lf;
  }
}

__global__ __launch_bounds__(64) void cumsum_kernel(float* __restrict__ c, int S) {
  const int b = blockIdx.x >> 4, h = blockIdx.x & 15;
  const int lane = threadIdx.x;
  float carry = 0.f;
  for (int s0 = 0; s0 < S; s0 += 64) {
    float v = c[(size_t)(b * S + s0 + lane) * 16 + h];
    #pragma unroll
    for (int off = 1; off < 64; off <<= 1) {
      float t = __shfl_up(v, off, 64);
      if (lane >= off) v += t;
    }
    v += carry;
    c[(size_t)(b * S + s0 + lane) * 16 + h] = v;
    carry = __shfl(v, 63, 64);
  }
}

// ---------------------------------------------------------------------------
// V^T prep: qkvb V-part (token-major) -> vtg[(b,h,d), s] bf16
// ---------------------------------------------------------------------------
__global__ __launch_bounds__(256) void vtrans(
    const u16* __restrict__ qkvb, u16* __restrict__ vtg) {
  __shared__ u16 t[32][33];
  const int bh = blockIdx.z, b = bh >> 4, h = bh & 15;
  const int s0 = blockIdx.x * 32, d0 = blockIdx.y * 32;
  const int tx = threadIdx.x & 31, ty = threadIdx.x >> 5;
  for (int i = ty; i < 32; i += 8)
    t[i][tx] = qkvb[(size_t)(b * 2048 + s0 + i) * 3072 + 2048 + h * 64 + d0 + tx];
  __syncthreads();
  for (int i = ty; i < 32; i += 8)
    vtg[(size_t)(bh * 64 + d0 + i) * 2048 + s0 + tx] = t[tx][i];
}

// ---------------------------------------------------------------------------
// MFMA flash attention with forget-gate decay bias. WORK-STEALING (512 blocks,
// LPT order) + round-9 changes:
//  - K/V/cj register prefetch pipeline: tile jt+1 loads overlap tile jt
//    compute (round-8: synchronous staging left load latency on the critical
//    path every tile -> VALUBusy 37%, MfmaUtil 7.6%, >50% no-pipe time)
//  - exp2-domain softmax (log2e folded into scale/ci/cj; one v_exp_f32/score)
//  - deferred l-reduction (per-lane partials; one 16-lane reduce per item)
//  - Q fragments hoisted out of the j-loop
// ---------------------------------------------------------------------------
#define FS 72
#define NITEMS 1024  // 32 q-tiles * 32 bh
#define L2E 1.4426950408889634f

__global__ __launch_bounds__(256) void fattn(
    const u16* __restrict__ qkvb, const u16* __restrict__ vtg,
    const float* __restrict__ c, u16* __restrict__ ctx, u32* __restrict__ ctr) {
  __shared__ u16 Qs[64 * FS];
  __shared__ u16 Ks[64 * FS];
  __shared__ u16 Vt[64 * FS];
  __shared__ u16 Ps[64 * FS];
  __shared__ float cjs[64];
  __shared__ u32 sh_item;
  const int S = 2048;
  const int tid = threadIdx.x, wave = tid >> 6, lane = tid & 63;
  const int lr = lane & 15, quad = lane >> 4;
  const int w16 = wave * 16;
  const int sr = tid >> 2, scc = (tid & 3) * 16;  // staging row/col

  for (;;) {
    if (tid == 0) sh_item = atomicAdd(ctr, 1u);
    __syncthreads();  // publish item (prev item's LDS reads already fenced)
    const u32 item = sh_item;
    if (item >= NITEMS) return;
    const int qt = 31 - (int)(item >> 5);       // descending work
    const int bh = (int)(item & 31), b = bh >> 4, h = bh & 15;
    const int i0 = qt * 64;

    {  // stage Q tile (64x64 bf16)
      const u16* src = qkvb + (size_t)(b * S + i0 + sr) * 3072 + h * 64 + scc;
      *(u32x4*)&Qs[sr * FS + scc] = *(const u32x4*)src;
      *(u32x4*)&Qs[sr * FS + scc + 8] = *(const u32x4*)(src + 8);
    }
    // prefetch K/V/cj for tile 0 into registers
    u32x4 kr0, kr1, vr0, vr1;
    float cjr = 0.f;
    {
      const u16* ks = qkvb + (size_t)(b * S + sr) * 3072 + 1024 + h * 64 + scc;
      kr0 = *(const u32x4*)ks;
      kr1 = *(const u32x4*)(ks + 8);
      const u16* vs = vtg + (size_t)(bh * 64 + sr) * 2048 + scc;
      vr0 = *(const u32x4*)vs;
      vr1 = *(const u32x4*)(vs + 8);
      if (tid < 64) cjr = c[(size_t)(b * S + tid) * 16 + h];
    }
    float ci[4], m_[4], l_[4], alpha[4];
    f32x4 o_[4];
    #pragma unroll
    for (int r = 0; r < 4; ++r) {
      ci[r] = c[(size_t)(b * S + i0 + w16 + quad * 4 + r) * 16 + h] * L2E;
      m_[r] = -INFINITY;
      l_[r] = 0.f;
    }
    #pragma unroll
    for (int dt = 0; dt < 4; ++dt) o_[dt] = (f32x4){0.f, 0.f, 0.f, 0.f};

    __syncthreads();  // Q visible
    const bf16x8 aq0 = *(const bf16x8*)&Qs[(w16 + lr) * FS + quad * 8];
    const bf16x8 aq1 = *(const bf16x8*)&Qs[(w16 + lr) * FS + 32 + quad * 8];

    const int ntiles = qt + 1;
    for (int jt = 0; jt < ntiles; ++jt) {
      const int j0 = jt * 64;
      // write prefetched tile jt to LDS (prev iter's reads fenced by barrier)
      *(u32x4*)&Ks[sr * FS + scc] = kr0;
      *(u32x4*)&Ks[sr * FS + scc + 8] = kr1;
      *(u32x4*)&Vt[sr * FS + scc] = vr0;
      *(u32x4*)&Vt[sr * FS + scc + 8] = vr1;
      if (tid < 64) cjs[tid] = cjr * L2E;
      // issue prefetch for tile jt+1 (completes during this tile's compute)
      if (jt + 1 < ntiles) {
        const int j1 = j0 + 64;
        const u16* ks = qkvb + (size_t)(b * S + j1 + sr) * 3072 + 1024 + h * 64 + scc;
        kr0 = *(const u32x4*)ks;
        kr1 = *(const u32x4*)(ks + 8);
        const u16* vs = vtg + (size_t)(bh * 64 + sr) * 2048 + j1 + scc;
        vr0 = *(const u32x4*)vs;
        vr1 = *(const u32x4*)(vs + 8);
        if (tid < 64) cjr = c[(size_t)(b * S + j1 + tid) * 16 + h];
      }
      __syncthreads();  // K/V visible

      f32x4 sc[4];
      #pragma unroll
      for (int nt = 0; nt < 4; ++nt) {
        bf16x8 bk0 = *(const bf16x8*)&Ks[(nt * 16 + lr) * FS + quad * 8];
        bf16x8 bk1 = *(const bf16x8*)&Ks[(nt * 16 + lr) * FS + 32 + quad * 8];
        f32x4 z = {0.f, 0.f, 0.f, 0.f};
        z = __builtin_amdgcn_mfma_f32_16x16x32_bf16(aq0, bk0, z, 0, 0, 0);
        z = __builtin_amdgcn_mfma_f32_16x16x32_bf16(aq1, bk1, z, 0, 0, 0);
        sc[nt] = z;
      }
      const bool diag = (jt == qt);
      #pragma unroll
      for (int r = 0; r < 4; ++r) {
        const int i = i0 + w16 + quad * 4 + r;
        float lg[4], mrow = -INFINITY;
        #pragma unroll
        for (int nt = 0; nt < 4; ++nt) {
          const int j = j0 + nt * 16 + lr;
          float v = sc[nt][r] * (0.125f * L2E) + ci[r] - cjs[nt * 16 + lr];
          if (diag && (j > i)) v = -INFINITY;
          lg[nt] = v;
          mrow = fmaxf(mrow, v);
        }
        #pragma unroll
        for (int off = 1; off < 16; off <<= 1)
          mrow = fmaxf(mrow, __shfl_xor(mrow, off, 64));
        const float mn = fmaxf(m_[r], mrow);
        alpha[r] = __builtin_exp2f(m_[r] - mn);
        m_[r] = mn;
        float rs = 0.f;
        #pragma unroll
        for (int nt = 0; nt < 4; ++nt) {
          const float p = __builtin_exp2f(lg[nt] - mn);
          Ps[(w16 + quad * 4 + r) * FS + nt * 16 + lr] = f2bf(p);
          rs += p;
        }
        l_[r] = l_[r] * alpha[r] + rs;  // per-lane partial (reduced at end)
      }
      // make this wave's P writes visible to its own b128 reads
      asm volatile("s_waitcnt lgkmcnt(0)" ::: "memory");
      #pragma unroll
      for (int dt = 0; dt < 4; ++dt)
        #pragma unroll
        for (int r = 0; r < 4; ++r) o_[dt][r] *= alpha[r];
      bf16x8 ap0 = *(const bf16x8*)&Ps[(w16 + lr) * FS + quad * 8];
      bf16x8 ap1 = *(const bf16x8*)&Ps[(w16 + lr) * FS + 32 + quad * 8];
      #pragma unroll
      for (int dt = 0; dt < 4; ++dt) {
        bf16x8 bv0 = *(const bf16x8*)&Vt[(dt * 16 + lr) * FS + quad * 8];
        bf16x8 bv1 = *(const bf16x8*)&Vt[(dt * 16 + lr) * FS + 32 + quad * 8];
        o_[dt] = __builtin_amdgcn_mfma_f32_16x16x32_bf16(ap0, bv0, o_[dt], 0, 0, 0);
        o_[dt] = __builtin_amdgcn_mfma_f32_16x16x32_bf16(ap1, bv1, o_[dt], 0, 0, 0);
      }
      __syncthreads();  // all reads of Ks/Vt done before next iter's writes
    }
    #pragma unroll
    for (int r = 0; r < 4; ++r) {
      float lt = l_[r];
      #pragma unroll
      for (int off = 1; off < 16; off <<= 1) lt += __shfl_xor(lt, off, 64);
      const float inv = 1.0f / lt;
      const size_t base = (size_t)(b * S + i0 + w16 + quad * 4 + r) * 1024 + h * 64;
      #pragma unroll
      for (int dt = 0; dt < 4; ++dt)
        ctx[base + dt * 16 + lr] = f2bf(o_[dt][r] * inv);
    }
  }
}

// ---------------------------------------------------------------------------
extern "C" void kernel_launch(void* const* d_in, const int* in_sizes, int n_in,
                              void* d_out, int out_size, void* d_ws, size_t ws_size,
                              hipStream_t stream) {
  const float* x    = (const float*)d_in[0];
  const float* ln1g = (const float*)d_in[1];
  const float* ln1b = (const float*)d_in[2];
  const float* wq   = (const float*)d_in[3];
  const float* bq   = (const float*)d_in[4];
  const float* wk   = (const float*)d_in[5];
  const float* bk   = (const float*)d_in[6];
  const float* wv   = (const float*)d_in[7];
  const float* bv   = (const float*)d_in[8];
  const float* wo   = (const float*)d_in[9];
  const float* bo   = (const float*)d_in[10];
  const float* wf   = (const float*)d_in[11];
  const float* bfv  = (const float*)d_in[12];
  const float* ln2g = (const float*)d_in[13];
  const float* ln2b = (const float*)d_in[14];
  const float* w1   = (const float*)d_in[15];
  const float* b1   = (const float*)d_in[16];
  const float* w2   = (const float*)d_in[17];
  const float* b2   = (const float*)d_in[18];
  float* out = (float*)d_out;

  char* ws = (char*)d_ws;
  const size_t MB = 1024 * 1024;
  u16*   wqkvT = (u16*)(ws + 0 * MB);        // 3072x1024 bf16 (6 MB)
  u16*   woT   = (u16*)(ws + 6 * MB);        // 1024x1024 bf16
  u16*   w1T   = (u16*)(ws + 8 * MB);        // 4096x1024 bf16
  u16*   w2T   = (u16*)(ws + 16 * MB);       // 1024x4096 bf16
  u16*   wfT   = (u16*)(ws + 24 * MB);       // 16x1024 bf16
  float* bqkv  = (float*)(ws + 24 * MB + 65536);  // 3072 fp32
  u32*   fctr  = (u32*)(ws + 24 * MB + 131072);   // work-steal counter
  u16*   hbuf  = (u16*)(ws + 25 * MB);       // 4096x1024 bf16
  u16*   ctx   = (u16*)(ws + 33 * MB);       // 4096x1024 bf16
  u16*   qkvb  = (u16*)(ws + 41 * MB);       // 4096x3072 bf16 (24 MB)
  u16*   vtg   = (u16*)(ws + 65 * MB);       // (32*64)x2048 bf16 (8 MB)
  float* cb    = (float*)(ws + 73 * MB);     // 4096x16 fp32
  u16*   act1  = (u16*)(ws + 74 * MB);       // 4096x4096 bf16 (32 MB)

  dim3 blk(256);
  // weight prep (pack3 also zeroes the fattn work-steal counter, on-stream)
  transpose_cast<<<dim3(32, 32), blk, 0, stream>>>(wq, wqkvT, 1024, 1024);
  transpose_cast<<<dim3(32, 32), blk, 0, stream>>>(wk, wqkvT + 1024 * 1024, 1024, 1024);
  transpose_cast<<<dim3(32, 32), blk, 0, stream>>>(wv, wqkvT + 2 * 1024 * 1024, 1024, 1024);
  transpose_cast<<<dim3(32, 32), blk, 0, stream>>>(wo, woT, 1024, 1024);
  transpose_cast<<<dim3(128, 32), blk, 0, stream>>>(w1, w1T, 1024, 4096);
  transpose_cast<<<dim3(32, 128), blk, 0, stream>>>(w2, w2T, 4096, 1024);
  transpose_cast<<<dim3(1, 32), blk, 0, stream>>>(wf, wfT, 1024, 16);
  pack3<<<12, blk, 0, stream>>>(bq, bk, bv, bqkv, fctr);
  // LN1
  ln_kernel<<<4096, blk, 0, stream>>>(x, ln1g, ln1b, hbuf);
  // fused QKV projection -> bf16 (4096 x 3072), 768 blocks = 3/CU
  gemm_bt<<<dim3(24, 32), blk, 0, stream>>>(hbuf, wqkvT, bqkv, nullptr, qkvb,
                                            4096, 3072, 1024, 3);
  // forget gate
  logf_kernel<<<4096, dim3(64), 0, stream>>>(hbuf, wfT, bfv, cb);
  cumsum_kernel<<<32, dim3(64), 0, stream>>>(cb, 2048);
  // V^T prep + attention (work-stealing; counter zeroed by pack3)
  vtrans<<<dim3(64, 2, 32), blk, 0, stream>>>(qkvb, vtg);
  fattn<<<dim3(512), blk, 0, stream>>>(qkvb, vtg, cb, ctx, fctr);
  // out projection + residual -> d_out (N=1024: n64 tiles, 512 blocks = 2/CU)
  gemm_n64<<<dim3(16, 32), blk, 0, stream>>>(ctx, woT, bo, x, out,
                                             4096, 1024, 1024, 1);
  // LN2
  ln_kernel<<<4096, blk, 0, stream>>>(out, ln2g, ln2b, hbuf);
  // MLP1: 1024 blocks = 4/CU
  gemm_bt<<<dim3(32, 32), blk, 0, stream>>>(hbuf, w1T, b1, nullptr, act1,
                                            4096, 4096, 1024, 2);
  // MLP2 (N=1024: n64 tiles, 512 blocks = 2/CU)
  gemm_n64<<<dim3(16, 32), blk, 0, stream>>>(act1, w2T, b2, out, out,
                                             4096, 1024, 4096, 1);
}